// Round 1
// baseline (691.679 us; speedup 1.0000x reference)
//
#include <hip/hip_runtime.h>

#define AS1 __attribute__((address_space(1)))
#define AS3 __attribute__((address_space(3)))

typedef __attribute__((ext_vector_type(4))) float f32x4;
typedef __attribute__((ext_vector_type(8))) short s16x8;

static __device__ __forceinline__ ushort f2bf(float f) {
  union { float f; unsigned u; } x; x.f = f;
  unsigned r = x.u + 0x7FFFu + ((x.u >> 16) & 1u);
  return (ushort)(r >> 16);
}

static __device__ __forceinline__ float parse_scalar(const void* p) {
  int i = *(const int*)p;
  if (i > 0 && i < 1000000) return (float)i;   // plausibly an integer temperature
  union { int i; float f; } u; u.i = i; return u.f; // else float bits
}

// ---------------- transpose + convert weights: in f32 [K][N] -> out bf16 [N][K]
__global__ __launch_bounds__(256)
void transpose_cvt(const float* __restrict__ in, ushort* __restrict__ out, int K, int N)
{
  __shared__ float tile[32][33];
  const size_t msz = (size_t)K * N;
  in += msz * blockIdx.z;
  out += msz * blockIdx.z;
  int nb = blockIdx.x * 32, kb = blockIdx.y * 32;
  int tx = threadIdx.x, ty = threadIdx.y;
  #pragma unroll
  for (int i = 0; i < 4; ++i)
    tile[ty + i * 8][tx] = in[(size_t)(kb + ty + i * 8) * N + nb + tx];
  __syncthreads();
  #pragma unroll
  for (int i = 0; i < 4; ++i)
    out[(size_t)(nb + ty + i * 8) * K + kb + tx] = f2bf(tile[tx][ty + i * 8]);
}

__global__ __launch_bounds__(256)
void cvt_bf16(const float* __restrict__ in, ushort* __restrict__ out, int n)
{
  int i = (blockIdx.x * 256 + threadIdx.x) * 4;
  if (i >= n) return;
  float4 v = *(const float4*)(in + i);
  ushort4 o;
  o.x = f2bf(v.x); o.y = f2bf(v.y); o.z = f2bf(v.z); o.w = f2bf(v.w);
  *(ushort4*)(out + i) = o;
}

// ---------------- GEMM: C[M][N] = A[M][K](bf16) @ Bt[N][K](bf16) + bias
// mode bits: 1 = write f32, 2 = write bf16, 4 = exact GELU before write
#define GBM 128
#define GBN 64
#define GBK 32

__global__ __launch_bounds__(256)
void gemm_bf16(const ushort* __restrict__ A, const ushort* __restrict__ Bt,
               const float* __restrict__ bias, float* __restrict__ outf,
               ushort* __restrict__ outb, int M, int N, int K, int mode,
               const void* scale_ptr)
{
  __shared__ ushort As[GBM * GBK]; // 8 KB
  __shared__ ushort Bs[GBN * GBK]; // 4 KB
  const int t = threadIdx.x;
  const int lane = t & 63;
  const int w = t >> 6;
  const int lr = lane & 15, g = lane >> 4;
  const int wr = w >> 1, wc = w & 1;
  const int m0 = blockIdx.y * GBM, n0 = blockIdx.x * GBN;

  f32x4 acc[4][2];
  f32x4 zero = {0.f, 0.f, 0.f, 0.f};
  #pragma unroll
  for (int m = 0; m < 4; ++m)
    #pragma unroll
    for (int n = 0; n < 2; ++n)
      acc[m][n] = zero;

  for (int kt = 0; kt < K; kt += GBK) {
    // stage A: 512 x 16B chunks (2/thread), self-inverse slot swizzle
    #pragma unroll
    for (int p = 0; p < 2; ++p) {
      int c = p * 256 + t;
      int row = c >> 2;
      int ls = (c & 3) ^ ((row >> 1) & 3);
      const ushort* gp = A + (size_t)(m0 + row) * K + kt + ls * 8;
      __builtin_amdgcn_global_load_lds((const AS1 void*)gp,
          (AS3 void*)(As + (size_t)(p * 256 + (t & ~63)) * 8), 16, 0, 0);
    }
    // stage B: 256 chunks (1/thread)
    {
      int row = t >> 2;
      int ls = (t & 3) ^ ((row >> 1) & 3);
      const ushort* gp = Bt + (size_t)(n0 + row) * K + kt + ls * 8;
      __builtin_amdgcn_global_load_lds((const AS1 void*)gp,
          (AS3 void*)(Bs + (size_t)(t & ~63) * 8), 16, 0, 0);
    }
    __syncthreads();
    s16x8 af[4], bfv[2];
    #pragma unroll
    for (int m = 0; m < 4; ++m) {
      int row = wr * 64 + m * 16 + lr;
      af[m] = *(const s16x8*)(As + row * GBK + (g ^ ((row >> 1) & 3)) * 8);
    }
    #pragma unroll
    for (int n = 0; n < 2; ++n) {
      int row = wc * 32 + n * 16 + lr;
      bfv[n] = *(const s16x8*)(Bs + row * GBK + (g ^ ((row >> 1) & 3)) * 8);
    }
    #pragma unroll
    for (int m = 0; m < 4; ++m)
      #pragma unroll
      for (int n = 0; n < 2; ++n)
        acc[m][n] = __builtin_amdgcn_mfma_f32_16x16x32_bf16(af[m], bfv[n], acc[m][n], 0, 0, 0);
    __syncthreads();
  }

  float sc = 1.0f;
  if (scale_ptr) sc = 0.125f / parse_scalar(scale_ptr);
  #pragma unroll
  for (int n = 0; n < 2; ++n) {
    int col = n0 + wc * 32 + n * 16 + lr;
    float bv = bias ? bias[col] : 0.f;
    #pragma unroll
    for (int m = 0; m < 4; ++m) {
      int rowb = m0 + wr * 64 + m * 16 + 4 * g;
      #pragma unroll
      for (int r = 0; r < 4; ++r) {
        float v = (acc[m][n][r] + bv) * sc;
        if (mode & 4) v = 0.5f * v * (1.0f + erff(v * 0.70710678118654752f));
        size_t idx = (size_t)(rowb + r) * N + col;
        if (mode & 1) outf[idx] = v;
        if (mode & 2) outb[idx] = f2bf(v);
      }
    }
  }
}

// ---------------- fused flash attention core (S=1024, D=64, NH=8)
// Q pre-scaled. Q,K,V,O: [B][1024][512] bf16, head = blockIdx.y, batch = blockIdx.z
__global__ __launch_bounds__(256)
void attn_core(const ushort* __restrict__ Q, const ushort* __restrict__ Kx,
               const ushort* __restrict__ V, ushort* __restrict__ O)
{
  __shared__ ushort Ks[64 * 64];     // [key][d], swizzled
  __shared__ ushort Vs[64 * 64];     // [d][key], swizzled
  __shared__ ushort Ps[4][16 * 64];  // per-wave [q][key], swizzled
  const int t = threadIdx.x, lane = t & 63, w = t >> 6;
  const int lr = lane & 15, g = lane >> 4;
  const size_t base = ((size_t)blockIdx.z * 1024) * 512 + blockIdx.y * 64;
  const int q0 = blockIdx.x * 64 + w * 16;

  s16x8 qf[2];
  #pragma unroll
  for (int ks = 0; ks < 2; ++ks)
    qf[ks] = *(const s16x8*)(Q + base + (size_t)(q0 + lr) * 512 + ks * 32 + g * 8);

  f32x4 po[4];
  f32x4 zero = {0.f, 0.f, 0.f, 0.f};
  #pragma unroll
  for (int dt = 0; dt < 4; ++dt) po[dt] = zero;
  float mrow[4] = {-1e30f, -1e30f, -1e30f, -1e30f};
  float lsum[4] = {0.f, 0.f, 0.f, 0.f};

  for (int kt = 0; kt < 16; ++kt) {
    __syncthreads(); // previous iteration's readers done before restage
    #pragma unroll
    for (int p = 0; p < 2; ++p) {
      int c = p * 256 + t;
      int row = c >> 3, slot = c & 7;
      s16x8 kv = *(const s16x8*)(Kx + base + (size_t)(kt * 64 + row) * 512 + slot * 8);
      int ka = (row * 128 + slot * 16) ^ ((row & 7) << 4);
      *(s16x8*)((char*)Ks + ka) = kv;
      s16x8 vv = *(const s16x8*)(V + base + (size_t)(kt * 64 + row) * 512 + slot * 8);
      #pragma unroll
      for (int j = 0; j < 8; ++j) {
        int d = slot * 8 + j;
        int va = (d * 128 + row * 2) ^ ((((d & 7) ^ ((d >> 3) & 7))) << 4);
        *(ushort*)((char*)Vs + va) = (ushort)vv[j];
      }
    }
    __syncthreads();
    // scores: S[q][key] for 64 keys
    f32x4 scv[4];
    #pragma unroll
    for (int c = 0; c < 4; ++c) {
      scv[c] = zero;
      #pragma unroll
      for (int ks = 0; ks < 2; ++ks) {
        int row = c * 16 + lr;
        int ka = (row * 128 + ks * 64 + g * 16) ^ ((row & 7) << 4);
        s16x8 kf = *(const s16x8*)((char*)Ks + ka);
        scv[c] = __builtin_amdgcn_mfma_f32_16x16x32_bf16(qf[ks], kf, scv[c], 0, 0, 0);
      }
    }
    // online softmax update (per lane: rows 4g+r)
    #pragma unroll
    for (int r = 0; r < 4; ++r) {
      float tm = fmaxf(fmaxf(scv[0][r], scv[1][r]), fmaxf(scv[2][r], scv[3][r]));
      #pragma unroll
      for (int msk = 1; msk < 16; msk <<= 1) tm = fmaxf(tm, __shfl_xor(tm, msk));
      float nm = fmaxf(mrow[r], tm);
      float fr = __expf(mrow[r] - nm);
      float ps = 0.f;
      #pragma unroll
      for (int c = 0; c < 4; ++c) {
        float pv = __expf(scv[c][r] - nm);
        scv[c][r] = pv;
        ps += pv;
      }
      #pragma unroll
      for (int msk = 1; msk < 16; msk <<= 1) ps += __shfl_xor(ps, msk);
      lsum[r] = lsum[r] * fr + ps;
      mrow[r] = nm;
      #pragma unroll
      for (int dt = 0; dt < 4; ++dt) po[dt][r] *= fr;
    }
    // P -> LDS (bf16), then read back in A-fragment layout
    #pragma unroll
    for (int c = 0; c < 4; ++c)
      #pragma unroll
      for (int r = 0; r < 4; ++r) {
        int qq = 4 * g + r, key = c * 16 + lr;
        int pa = (qq * 128 + key * 2) ^ ((qq & 7) << 4);
        *(ushort*)((char*)Ps[w] + pa) = f2bf(scv[c][r]);
      }
    __syncthreads();
    #pragma unroll
    for (int ks = 0; ks < 2; ++ks) {
      int pra = (lr * 128 + ks * 64 + g * 16) ^ ((lr & 7) << 4);
      s16x8 pfr = *(const s16x8*)((char*)Ps[w] + pra);
      #pragma unroll
      for (int dt = 0; dt < 4; ++dt) {
        int vrow = dt * 16 + lr;
        int va = (vrow * 128 + ks * 64 + g * 16) ^ ((((vrow & 7) ^ ((vrow >> 3) & 7))) << 4);
        s16x8 vf = *(const s16x8*)((char*)Vs + va);
        po[dt] = __builtin_amdgcn_mfma_f32_16x16x32_bf16(pfr, vf, po[dt], 0, 0, 0);
      }
    }
  }
  #pragma unroll
  for (int r = 0; r < 4; ++r) {
    float inv = 1.0f / lsum[r];
    #pragma unroll
    for (int dt = 0; dt < 4; ++dt) {
      size_t idx = base + (size_t)(q0 + 4 * g + r) * 512 + dt * 16 + lr;
      O[idx] = f2bf(po[dt][r] * inv);
    }
  }
}

// ---------------- out = LN(a + b) * scale + bias ; one wave per 512-row
__global__ __launch_bounds__(256)
void add_ln(const float* __restrict__ a, const float* __restrict__ b,
            const float* __restrict__ scale, const float* __restrict__ bias,
            float* __restrict__ outf, ushort* __restrict__ outb)
{
  const int lane = threadIdx.x & 63, w = threadIdx.x >> 6;
  const size_t row = blockIdx.x * 4 + w;
  const float* ar = a + row * 512;
  const float* br = b + row * 512;
  float x[8];
  #pragma unroll
  for (int j = 0; j < 8; j += 4) {
    float4 av = *(const float4*)(ar + lane * 8 + j);
    float4 bv = *(const float4*)(br + lane * 8 + j);
    x[j] = av.x + bv.x; x[j + 1] = av.y + bv.y;
    x[j + 2] = av.z + bv.z; x[j + 3] = av.w + bv.w;
  }
  float s = 0.f, ss = 0.f;
  #pragma unroll
  for (int j = 0; j < 8; ++j) { s += x[j]; ss += x[j] * x[j]; }
  #pragma unroll
  for (int m = 1; m < 64; m <<= 1) { s += __shfl_xor(s, m); ss += __shfl_xor(ss, m); }
  float mu = s * (1.f / 512.f);
  float var = ss * (1.f / 512.f) - mu * mu;
  float rstd = rsqrtf(var + 1e-5f);
  #pragma unroll
  for (int j = 0; j < 8; ++j) {
    int e = lane * 8 + j;
    float v = (x[j] - mu) * rstd * scale[e] + bias[e];
    outf[row * 512 + e] = v;
    if (outb) outb[row * 512 + e] = f2bf(v);
  }
}

// ---------------- gated merge + LN: out = LN(x*g0 + cr*g1), g = softmax([x,cr]@gw+gb)
__global__ __launch_bounds__(256)
void gate_ln(const float* __restrict__ x, const float* __restrict__ cr,
             const float* __restrict__ gw, const float* __restrict__ gb,
             const float* __restrict__ scale, const float* __restrict__ bias,
             float* __restrict__ outf, ushort* __restrict__ outb)
{
  const int lane = threadIdx.x & 63, w = threadIdx.x >> 6;
  const size_t row = blockIdx.x * 4 + w;
  const float* xr = x + row * 512;
  const float* cc = cr + row * 512;
  float xv[8], cv[8];
  #pragma unroll
  for (int j = 0; j < 8; j += 4) {
    *(float4*)(xv + j) = *(const float4*)(xr + lane * 8 + j);
    *(float4*)(cv + j) = *(const float4*)(cc + lane * 8 + j);
  }
  float d0 = 0.f, d1 = 0.f;
  #pragma unroll
  for (int j = 0; j < 8; ++j) {
    int e = lane * 8 + j;
    float2 g0 = *(const float2*)(gw + 2 * e);
    float2 g1 = *(const float2*)(gw + 2 * (512 + e));
    d0 += xv[j] * g0.x + cv[j] * g1.x;
    d1 += xv[j] * g0.y + cv[j] * g1.y;
  }
  #pragma unroll
  for (int m = 1; m < 64; m <<= 1) { d0 += __shfl_xor(d0, m); d1 += __shfl_xor(d1, m); }
  d0 += gb[0]; d1 += gb[1];
  float mx = fmaxf(d0, d1);
  float e0 = __expf(d0 - mx), e1 = __expf(d1 - mx);
  float inv = 1.0f / (e0 + e1);
  float g0w = e0 * inv, g1w = e1 * inv;
  float xc[8];
  float s = 0.f, ss = 0.f;
  #pragma unroll
  for (int j = 0; j < 8; ++j) {
    xc[j] = xv[j] * g0w + cv[j] * g1w;
    s += xc[j]; ss += xc[j] * xc[j];
  }
  #pragma unroll
  for (int m = 1; m < 64; m <<= 1) { s += __shfl_xor(s, m); ss += __shfl_xor(ss, m); }
  float mu = s * (1.f / 512.f);
  float var = ss * (1.f / 512.f) - mu * mu;
  float rstd = rsqrtf(var + 1e-5f);
  #pragma unroll
  for (int j = 0; j < 8; ++j) {
    int e = lane * 8 + j;
    float v = (xc[j] - mu) * rstd * scale[e] + bias[e];
    outf[row * 512 + e] = v;
    if (outb) outb[row * 512 + e] = f2bf(v);
  }
}

extern "C" void kernel_launch(void* const* d_in, const int* in_sizes, int n_in,
                              void* d_out, int out_size, void* d_ws, size_t ws_size,
                              hipStream_t stream)
{
  (void)in_sizes; (void)n_in; (void)out_size; (void)ws_size;
  const int T = 4096, E = 512, HD = 2048;
  const float* body = (const float*)d_in[0];
  const float* limb = (const float*)d_in[1];
  const float* qw = (const float*)d_in[2];  const float* qb = (const float*)d_in[3];
  const float* kw = (const float*)d_in[4];  const float* kb = (const float*)d_in[5];
  const float* vw = (const float*)d_in[6];  const float* vb = (const float*)d_in[7];
  const float* ow = (const float*)d_in[8];  const float* ob = (const float*)d_in[9];
  const float* w1 = (const float*)d_in[10]; const float* b1 = (const float*)d_in[11];
  const float* w2 = (const float*)d_in[12]; const float* b2 = (const float*)d_in[13];
  const float* nsc = (const float*)d_in[14]; const float* nbi = (const float*)d_in[15];
  const float* gw = (const float*)d_in[16];  const float* gb = (const float*)d_in[17];
  const void* temp = d_in[18];

  char* ws = (char*)d_ws;
  size_t off = 0;
  auto alloc = [&](size_t b) { char* p = ws + off; off += (b + 255) & ~(size_t)255; return p; };
  ushort* WQT   = (ushort*)alloc((size_t)4 * E * E * 2);
  ushort* WKT   = (ushort*)alloc((size_t)4 * E * E * 2);
  ushort* WVT   = (ushort*)alloc((size_t)4 * E * E * 2);
  ushort* WOT   = (ushort*)alloc((size_t)4 * E * E * 2);
  ushort* W1T   = (ushort*)alloc((size_t)2 * E * HD * 2);
  ushort* W2T   = (ushort*)alloc((size_t)2 * HD * E * 2);
  ushort* XB    = (ushort*)alloc((size_t)T * E * 2);
  ushort* XL    = (ushort*)alloc((size_t)T * E * 2);
  ushort* Qb    = (ushort*)alloc((size_t)T * E * 2);
  ushort* Kb    = (ushort*)alloc((size_t)T * E * 2);
  ushort* Vb    = (ushort*)alloc((size_t)T * E * 2);
  ushort* AOb   = (ushort*)alloc((size_t)T * E * 2);
  float*  PROJ  = (float*)alloc((size_t)T * E * 4);
  float*  BODYf = (float*)alloc((size_t)T * E * 4);
  float*  LIMBf = (float*)alloc((size_t)T * E * 4);
  ushort* BODYb = (ushort*)alloc((size_t)T * E * 2);
  ushort* LIMBb = (ushort*)alloc((size_t)T * E * 2);
  float*  BCRf  = (float*)alloc((size_t)T * E * 4);
  float*  LCRf  = (float*)alloc((size_t)T * E * 4);
  float*  GBf   = (float*)alloc((size_t)T * E * 4);
  float*  GLf   = (float*)alloc((size_t)T * E * 4);
  ushort* GBb   = (ushort*)alloc((size_t)T * E * 2);
  ushort* GLb   = (ushort*)alloc((size_t)T * E * 2);
  ushort* H1b   = Qb;   // reuse 16MB region Qb..AOb (dead after cross-attn)
  float*  FFNf  = PROJ; // reuse

  dim3 tb(32, 8);
  transpose_cvt<<<dim3(E / 32, E / 32, 4), tb, 0, stream>>>(qw, WQT, E, E);
  transpose_cvt<<<dim3(E / 32, E / 32, 4), tb, 0, stream>>>(kw, WKT, E, E);
  transpose_cvt<<<dim3(E / 32, E / 32, 4), tb, 0, stream>>>(vw, WVT, E, E);
  transpose_cvt<<<dim3(E / 32, E / 32, 4), tb, 0, stream>>>(ow, WOT, E, E);
  transpose_cvt<<<dim3(HD / 32, E / 32, 2), tb, 0, stream>>>(w1, W1T, E, HD);
  transpose_cvt<<<dim3(E / 32, HD / 32, 2), tb, 0, stream>>>(w2, W2T, HD, E);
  cvt_bf16<<<T * E / 1024, 256, 0, stream>>>(body, XB, T * E);
  cvt_bf16<<<T * E / 1024, 256, 0, stream>>>(limb, XL, T * E);

  auto gemm = [&](const ushort* Ain, const ushort* Bt, const float* bias,
                  float* of, ushort* ob2, int M, int N, int K, int mode, const void* sp) {
    gemm_bf16<<<dim3(N / GBN, M / GBM), 256, 0, stream>>>(Ain, Bt, bias, of, ob2, M, N, K, mode, sp);
  };

  // self attention + residual LN
  for (int s = 0; s < 2; ++s) {
    const ushort* X = s ? XL : XB;
    const float* resid = s ? limb : body;
    float* SFf = s ? LIMBf : BODYf;
    ushort* SFb = s ? LIMBb : BODYb;
    int lni = s ? 3 : 0;
    size_t io = (size_t)s * E * E;
    gemm(X, WQT + io, qb + s * E, nullptr, Qb, T, E, E, 2, temp);
    gemm(X, WKT + io, kb + s * E, nullptr, Kb, T, E, E, 2, nullptr);
    gemm(X, WVT + io, vb + s * E, nullptr, Vb, T, E, E, 2, nullptr);
    attn_core<<<dim3(16, 8, 4), 256, 0, stream>>>(Qb, Kb, Vb, AOb);
    gemm(AOb, WOT + io, ob + s * E, PROJ, nullptr, T, E, E, 1, nullptr);
    add_ln<<<T / 4, 256, 0, stream>>>(resid, PROJ, nsc + lni * E, nbi + lni * E, SFf, SFb);
  }
  // cross attention (no residual/LN on output)
  for (int s = 0; s < 2; ++s) {
    int i = 2 + s;
    const ushort* Qx = s ? LIMBb : BODYb;
    const ushort* KVx = s ? BODYb : LIMBb;
    float* CRf = s ? LCRf : BCRf;
    size_t io = (size_t)i * E * E;
    gemm(Qx, WQT + io, qb + i * E, nullptr, Qb, T, E, E, 2, temp);
    gemm(KVx, WKT + io, kb + i * E, nullptr, Kb, T, E, E, 2, nullptr);
    gemm(KVx, WVT + io, vb + i * E, nullptr, Vb, T, E, E, 2, nullptr);
    attn_core<<<dim3(16, 8, 4), 256, 0, stream>>>(Qb, Kb, Vb, AOb);
    gemm(AOb, WOT + io, ob + i * E, CRf, nullptr, T, E, E, 1, nullptr);
  }
  // gated merge + LN (both streams use norm index 1, faithful to reference)
  gate_ln<<<T / 4, 256, 0, stream>>>(BODYf, BCRf, gw, gb, nsc + E, nbi + E, GBf, GBb);
  gate_ln<<<T / 4, 256, 0, stream>>>(LIMBf, LCRf, gw, gb, nsc + E, nbi + E, GLf, GLb);
  // FFN + residual LN -> final outputs
  for (int s = 0; s < 2; ++s) {
    const ushort* Xg = s ? GLb : GBb;
    const float* Xf = s ? GLf : GBf;
    int lni = s ? 5 : 2;
    gemm(Xg, W1T + (size_t)s * E * HD, b1 + s * HD, nullptr, H1b, T, HD, E, 2 | 4, nullptr);
    gemm(H1b, W2T + (size_t)s * HD * E, b2 + s * E, FFNf, nullptr, T, E, HD, 1, nullptr);
    add_ln<<<T / 4, 256, 0, stream>>>(Xf, FFNf, nsc + lni * E, nbi + lni * E,
                                      (float*)d_out + (size_t)s * T * E, nullptr);
  }
}

// Round 2
// 659.891 us; speedup vs baseline: 1.0482x; 1.0482x over previous
//
#include <hip/hip_runtime.h>

#define AS1 __attribute__((address_space(1)))
#define AS3 __attribute__((address_space(3)))

typedef __attribute__((ext_vector_type(4))) float f32x4;
typedef __attribute__((ext_vector_type(8))) short s16x8;

static __device__ __forceinline__ ushort f2bf(float f) {
  union { float f; unsigned u; } x; x.f = f;
  unsigned r = x.u + 0x7FFFu + ((x.u >> 16) & 1u);
  return (ushort)(r >> 16);
}
static __device__ __forceinline__ float bf2f(ushort u) {
  union { unsigned u; float f; } x; x.u = ((unsigned)u) << 16; return x.f;
}
static __device__ __forceinline__ float ex2(float x) {
  return __builtin_amdgcn_exp2f(x);
}
static __device__ __forceinline__ float parse_scalar(const void* p) {
  int i = *(const int*)p;
  if (i > 0 && i < 1000000) return (float)i;
  union { int i; float f; } u; u.i = i; return u.f;
}

// ---------------- generic transpose+cvt: in f32 [K][N] -> out bf16 [N][K], batched z
__global__ __launch_bounds__(256)
void transpose_cvt(const float* __restrict__ in, ushort* __restrict__ out, int K, int N)
{
  __shared__ float tile[32][33];
  const size_t msz = (size_t)K * N;
  in += msz * blockIdx.z;
  out += msz * blockIdx.z;
  int nb = blockIdx.x * 32, kb = blockIdx.y * 32;
  int tx = threadIdx.x, ty = threadIdx.y;
  #pragma unroll
  for (int i = 0; i < 4; ++i)
    tile[ty + i * 8][tx] = in[(size_t)(kb + ty + i * 8) * N + nb + tx];
  __syncthreads();
  #pragma unroll
  for (int i = 0; i < 4; ++i)
    out[(size_t)(nb + ty + i * 8) * K + kb + tx] = f2bf(tile[tx][ty + i * 8]);
}

// ---------------- fused QKV weight transpose: FW[trip][1536][512]
// trip t: q-index = t, kv-index = t ^ (t>>1)  ({0,1,3,2})
__global__ __launch_bounds__(256)
void transpose_qkv(const float* __restrict__ qw, const float* __restrict__ kw,
                   const float* __restrict__ vw, ushort* __restrict__ out)
{
  __shared__ float tile[32][33];
  int z = blockIdx.z;
  int trip = z / 3, which = z - trip * 3;
  int widx = (which == 0) ? trip : (trip ^ (trip >> 1));
  const float* in = ((which == 0) ? qw : (which == 1) ? kw : vw) + (size_t)widx * 512 * 512;
  ushort* o = out + (size_t)trip * 1536 * 512 + (size_t)which * 512 * 512;
  int nb = blockIdx.x * 32, kb = blockIdx.y * 32;
  int tx = threadIdx.x, ty = threadIdx.y;
  #pragma unroll
  for (int i = 0; i < 4; ++i)
    tile[ty + i * 8][tx] = in[(size_t)(kb + ty + i * 8) * 512 + nb + tx];
  __syncthreads();
  #pragma unroll
  for (int i = 0; i < 4; ++i)
    o[(size_t)(nb + ty + i * 8) * 512 + kb + tx] = f2bf(tile[tx][ty + i * 8]);
}

__global__ __launch_bounds__(256)
void cvt_bf16(const float* __restrict__ in, ushort* __restrict__ out, int n)
{
  int i = (blockIdx.x * 256 + threadIdx.x) * 4;
  if (i >= n) return;
  float4 v = *(const float4*)(in + i);
  ushort4 o;
  o.x = f2bf(v.x); o.y = f2bf(v.y); o.z = f2bf(v.z); o.w = f2bf(v.w);
  *(ushort4*)(out + i) = o;
}

// ---------------- GEMM: C[M][N] = A[M][K](bf16) @ Bt[N][K](bf16) + bias
// kind: 0 f32 out, 1 bf16 out, 2 bf16+GELU out, 3 QKV split (q scaled, k plain, v transposed per-head)
struct GemmArgs {
  const ushort* A; const ushort* Bt;
  const float *b0, *b1, *b2;
  float* outf; ushort* outb;
  ushort *qo, *ko, *vto;
  const void* sp;
  int M, N, K, kind;
};

template<int FM, int FN>
__global__ __launch_bounds__(256)
void gemm_k(GemmArgs g)
{
  constexpr int BM = FM * 32, BN = FN * 32;
  __shared__ ushort As[BM * 64];
  __shared__ ushort Bs[BN * 64];
  const int t = threadIdx.x, lane = t & 63, w = t >> 6;
  const int lr = lane & 15, gq = lane >> 4;
  const int wr = w >> 1, wc = w & 1;
  const int m0 = blockIdx.y * BM, n0 = blockIdx.x * BN;
  const int K = g.K;

  f32x4 acc[FM][FN];
  f32x4 zero = {0.f, 0.f, 0.f, 0.f};
  #pragma unroll
  for (int m = 0; m < FM; ++m)
    #pragma unroll
    for (int n = 0; n < FN; ++n) acc[m][n] = zero;

  for (int kt = 0; kt < K; kt += 64) {
    #pragma unroll
    for (int p = 0; p < FM; ++p) {
      int c = p * 256 + t, row = c >> 3, sl = c & 7;
      const ushort* src = g.A + (size_t)(m0 + row) * K + kt + ((sl ^ (row & 7)) << 3);
      __builtin_amdgcn_global_load_lds((const AS1 void*)src,
          (AS3 void*)(As + (size_t)(p * 256 + (t & ~63)) * 8), 16, 0, 0);
    }
    #pragma unroll
    for (int p = 0; p < FN; ++p) {
      int c = p * 256 + t, row = c >> 3, sl = c & 7;
      const ushort* src = g.Bt + (size_t)(n0 + row) * K + kt + ((sl ^ (row & 7)) << 3);
      __builtin_amdgcn_global_load_lds((const AS1 void*)src,
          (AS3 void*)(Bs + (size_t)(p * 256 + (t & ~63)) * 8), 16, 0, 0);
    }
    __syncthreads();
    #pragma unroll
    for (int ks = 0; ks < 2; ++ks) {
      s16x8 af[FM], bfv[FN];
      #pragma unroll
      for (int m = 0; m < FM; ++m) {
        int row = wr * (FM * 16) + m * 16 + lr;
        af[m] = *(const s16x8*)(As + row * 64 + (((ks * 4 + gq) ^ (row & 7)) << 3));
      }
      #pragma unroll
      for (int n = 0; n < FN; ++n) {
        int row = wc * (FN * 16) + n * 16 + lr;
        bfv[n] = *(const s16x8*)(Bs + row * 64 + (((ks * 4 + gq) ^ (row & 7)) << 3));
      }
      __builtin_amdgcn_s_setprio(1);
      #pragma unroll
      for (int m = 0; m < FM; ++m)
        #pragma unroll
        for (int n = 0; n < FN; ++n)
          acc[m][n] = __builtin_amdgcn_mfma_f32_16x16x32_bf16(af[m], bfv[n], acc[m][n], 0, 0, 0);
      __builtin_amdgcn_s_setprio(0);
    }
    __syncthreads();
  }

  float qs = 1.0f;
  if (g.kind == 3 && g.sp) qs = 0.125f / parse_scalar(g.sp) * 1.4426950408889634f;
  #pragma unroll
  for (int n = 0; n < FN; ++n) {
    int col = n0 + wc * (FN * 16) + n * 16 + lr;
    int seg = col >> 9, cm = col & 511;
    float bv;
    if (g.kind == 3) bv = (seg == 0) ? g.b0[cm] : (seg == 1) ? g.b1[cm] : g.b2[cm];
    else bv = g.b0 ? g.b0[col] : 0.f;
    #pragma unroll
    for (int m = 0; m < FM; ++m) {
      int rowb = m0 + wr * (FM * 16) + m * 16 + 4 * gq;
      if (g.kind == 3) {
        if (seg == 2) {
          int d = cm & 63, hh = cm >> 6, bb = rowb >> 10, s = rowb & 1023;
          ushort4 pk;
          pk.x = f2bf(acc[m][n][0] + bv); pk.y = f2bf(acc[m][n][1] + bv);
          pk.z = f2bf(acc[m][n][2] + bv); pk.w = f2bf(acc[m][n][3] + bv);
          *(ushort4*)(g.vto + (((size_t)(bb * 8 + hh) * 64 + d) << 10) + s) = pk;
        } else if (seg == 1) {
          #pragma unroll
          for (int r = 0; r < 4; ++r)
            g.ko[(size_t)(rowb + r) * 512 + cm] = f2bf(acc[m][n][r] + bv);
        } else {
          #pragma unroll
          for (int r = 0; r < 4; ++r)
            g.qo[(size_t)(rowb + r) * 512 + cm] = f2bf((acc[m][n][r] + bv) * qs);
        }
      } else {
        #pragma unroll
        for (int r = 0; r < 4; ++r) {
          float v = acc[m][n][r] + bv;
          if (g.kind == 2) v = 0.5f * v * (1.0f + erff(v * 0.70710678118654752f));
          if (g.kind == 0) g.outf[(size_t)(rowb + r) * g.N + col] = v;
          else g.outb[(size_t)(rowb + r) * g.N + col] = f2bf(v);
        }
      }
    }
  }
}

// ---------------- flash attention core, no K/V LDS staging (L1/L2-resident), no barriers
// Q pre-scaled by 0.125/temp*log2e. Q,K: [B*1024][512]; VT: [B*H][64][1024]; O: [B*1024][512]
__global__ __launch_bounds__(256)
void attn_core(const ushort* __restrict__ Q, const ushort* __restrict__ Kx,
               const ushort* __restrict__ VT, ushort* __restrict__ O)
{
  __shared__ ushort Ps[4][1024];
  const int t = threadIdx.x, lane = t & 63, w = t >> 6;
  const int lr = lane & 15, g = lane >> 4;
  int bid = blockIdx.x;
  int L = (bid & 7) * 64 + (bid >> 3);       // XCD-grouping swizzle (512 blocks, 8 XCDs)
  int bh = L >> 4, qt = L & 15;
  size_t tbase = ((size_t)(bh >> 3) << 19) + (size_t)((bh & 7) << 6); // b*1024*512 + h*64
  size_t vbase = (size_t)bh << 16;                                    // bh*64*1024
  int q0 = qt * 64 + w * 16;
  ushort* myPs = Ps[w];

  s16x8 qf[2];
  #pragma unroll
  for (int ks = 0; ks < 2; ++ks)
    qf[ks] = *(const s16x8*)(Q + tbase + (size_t)(q0 + lr) * 512 + ks * 32 + g * 8);

  f32x4 po[4];
  f32x4 zero = {0.f, 0.f, 0.f, 0.f};
  #pragma unroll
  for (int dt = 0; dt < 4; ++dt) po[dt] = zero;
  float mrow[4] = {-1e30f, -1e30f, -1e30f, -1e30f};
  float lsum[4] = {0.f, 0.f, 0.f, 0.f};

  #pragma unroll 2
  for (int kt = 0; kt < 16; ++kt) {
    const ushort* Kt = Kx + tbase + ((size_t)kt << 15);
    s16x8 kf[4][2];
    #pragma unroll
    for (int c = 0; c < 4; ++c)
      #pragma unroll
      for (int ks = 0; ks < 2; ++ks)
        kf[c][ks] = *(const s16x8*)(Kt + (size_t)(c * 16 + lr) * 512 + ks * 32 + g * 8);
    s16x8 vf[4][2];
    #pragma unroll
    for (int dt = 0; dt < 4; ++dt)
      #pragma unroll
      for (int ks = 0; ks < 2; ++ks)
        vf[dt][ks] = *(const s16x8*)(VT + vbase + (size_t)(dt * 16 + lr) * 1024 + kt * 64 + ks * 32 + g * 8);

    f32x4 sc[4];
    __builtin_amdgcn_s_setprio(1);
    #pragma unroll
    for (int c = 0; c < 4; ++c) {
      sc[c] = zero;
      #pragma unroll
      for (int ks = 0; ks < 2; ++ks)
        sc[c] = __builtin_amdgcn_mfma_f32_16x16x32_bf16(qf[ks], kf[c][ks], sc[c], 0, 0, 0);
    }
    __builtin_amdgcn_s_setprio(0);

    #pragma unroll
    for (int r = 0; r < 4; ++r) {
      float tm = fmaxf(fmaxf(sc[0][r], sc[1][r]), fmaxf(sc[2][r], sc[3][r]));
      #pragma unroll
      for (int msk = 1; msk < 16; msk <<= 1) tm = fmaxf(tm, __shfl_xor(tm, msk));
      float nm = fmaxf(mrow[r], tm);
      float fr = ex2(mrow[r] - nm);
      float ps = 0.f;
      #pragma unroll
      for (int c = 0; c < 4; ++c) {
        float pv = ex2(sc[c][r] - nm);
        sc[c][r] = pv;
        ps += pv;
      }
      #pragma unroll
      for (int msk = 1; msk < 16; msk <<= 1) ps += __shfl_xor(ps, msk);
      lsum[r] = lsum[r] * fr + ps;
      mrow[r] = nm;
      #pragma unroll
      for (int dt = 0; dt < 4; ++dt) po[dt][r] *= fr;
    }

    #pragma unroll
    for (int c = 0; c < 4; ++c)
      #pragma unroll
      for (int r = 0; r < 4; ++r) {
        int qq = 4 * g + r;
        int pa = (qq * 128 + (c * 16 + lr) * 2) ^ ((qq & 7) << 4);
        *(ushort*)((char*)myPs + pa) = f2bf(sc[c][r]);
      }
    s16x8 paf[2];
    #pragma unroll
    for (int ks = 0; ks < 2; ++ks)
      paf[ks] = *(const s16x8*)((char*)myPs + ((lr * 128 + ks * 64 + g * 16) ^ ((lr & 7) << 4)));
    __builtin_amdgcn_s_setprio(1);
    #pragma unroll
    for (int dt = 0; dt < 4; ++dt)
      #pragma unroll
      for (int ks = 0; ks < 2; ++ks)
        po[dt] = __builtin_amdgcn_mfma_f32_16x16x32_bf16(paf[ks], vf[dt][ks], po[dt], 0, 0, 0);
    __builtin_amdgcn_s_setprio(0);
  }

  #pragma unroll
  for (int r = 0; r < 4; ++r) {
    float inv = 1.0f / lsum[r];
    #pragma unroll
    for (int dt = 0; dt < 4; ++dt)
      O[tbase + (size_t)(q0 + 4 * g + r) * 512 + dt * 16 + lr] = f2bf(po[dt][r] * inv);
  }
}

// ---------------- LN(a_f32 + b_f32) -> bf16
__global__ __launch_bounds__(256)
void add_ln_ff(const float* __restrict__ a, const float* __restrict__ b,
               const float* __restrict__ scale, const float* __restrict__ bias,
               ushort* __restrict__ outb)
{
  const int lane = threadIdx.x & 63, w = threadIdx.x >> 6;
  const size_t row = blockIdx.x * 4 + w;
  const float* ar = a + row * 512;
  const float* br = b + row * 512;
  float x[8];
  #pragma unroll
  for (int j = 0; j < 8; j += 4) {
    float4 av = *(const float4*)(ar + lane * 8 + j);
    float4 bv = *(const float4*)(br + lane * 8 + j);
    x[j] = av.x + bv.x; x[j + 1] = av.y + bv.y;
    x[j + 2] = av.z + bv.z; x[j + 3] = av.w + bv.w;
  }
  float s = 0.f, ss = 0.f;
  #pragma unroll
  for (int j = 0; j < 8; ++j) { s += x[j]; ss += x[j] * x[j]; }
  #pragma unroll
  for (int m = 1; m < 64; m <<= 1) { s += __shfl_xor(s, m); ss += __shfl_xor(ss, m); }
  float mu = s * (1.f / 512.f);
  float rstd = rsqrtf(ss * (1.f / 512.f) - mu * mu + 1e-5f);
  ushort o[8];
  #pragma unroll
  for (int j = 0; j < 8; ++j) {
    int e = lane * 8 + j;
    o[j] = f2bf((x[j] - mu) * rstd * scale[e] + bias[e]);
  }
  *(s16x8*)(outb + row * 512 + lane * 8) = *(s16x8*)o;
}

// ---------------- LN(a_bf16 + b_f32) -> f32 (final outputs)
__global__ __launch_bounds__(256)
void add_ln_bf(const ushort* __restrict__ a, const float* __restrict__ b,
               const float* __restrict__ scale, const float* __restrict__ bias,
               float* __restrict__ outf)
{
  const int lane = threadIdx.x & 63, w = threadIdx.x >> 6;
  const size_t row = blockIdx.x * 4 + w;
  s16x8 av = *(const s16x8*)(a + row * 512 + lane * 8);
  float x[8];
  #pragma unroll
  for (int j = 0; j < 8; j += 4) {
    float4 bv = *(const float4*)(b + row * 512 + lane * 8 + j);
    x[j] = bf2f((ushort)av[j]) + bv.x; x[j + 1] = bf2f((ushort)av[j + 1]) + bv.y;
    x[j + 2] = bf2f((ushort)av[j + 2]) + bv.z; x[j + 3] = bf2f((ushort)av[j + 3]) + bv.w;
  }
  float s = 0.f, ss = 0.f;
  #pragma unroll
  for (int j = 0; j < 8; ++j) { s += x[j]; ss += x[j] * x[j]; }
  #pragma unroll
  for (int m = 1; m < 64; m <<= 1) { s += __shfl_xor(s, m); ss += __shfl_xor(ss, m); }
  float mu = s * (1.f / 512.f);
  float rstd = rsqrtf(ss * (1.f / 512.f) - mu * mu + 1e-5f);
  float o[8];
  #pragma unroll
  for (int j = 0; j < 8; ++j) {
    int e = lane * 8 + j;
    o[j] = (x[j] - mu) * rstd * scale[e] + bias[e];
  }
  *(float4*)(outf + row * 512 + lane * 8) = *(float4*)o;
  *(float4*)(outf + row * 512 + lane * 8 + 4) = *(float4*)(o + 4);
}

// ---------------- gated merge + LN, bf16 in/out
__global__ __launch_bounds__(256)
void gate_ln_bb(const ushort* __restrict__ x, const ushort* __restrict__ cr,
                const float* __restrict__ gw, const float* __restrict__ gb,
                const float* __restrict__ scale, const float* __restrict__ bias,
                ushort* __restrict__ outb)
{
  const int lane = threadIdx.x & 63, w = threadIdx.x >> 6;
  const size_t row = blockIdx.x * 4 + w;
  s16x8 xv8 = *(const s16x8*)(x + row * 512 + lane * 8);
  s16x8 cv8 = *(const s16x8*)(cr + row * 512 + lane * 8);
  float xv[8], cv[8];
  #pragma unroll
  for (int j = 0; j < 8; ++j) { xv[j] = bf2f((ushort)xv8[j]); cv[j] = bf2f((ushort)cv8[j]); }
  float d0 = 0.f, d1 = 0.f;
  #pragma unroll
  for (int j = 0; j < 8; ++j) {
    int e = lane * 8 + j;
    float2 g0 = *(const float2*)(gw + 2 * e);
    float2 g1 = *(const float2*)(gw + 2 * (512 + e));
    d0 += xv[j] * g0.x + cv[j] * g1.x;
    d1 += xv[j] * g0.y + cv[j] * g1.y;
  }
  #pragma unroll
  for (int m = 1; m < 64; m <<= 1) { d0 += __shfl_xor(d0, m); d1 += __shfl_xor(d1, m); }
  d0 += gb[0]; d1 += gb[1];
  float mx = fmaxf(d0, d1);
  float e0 = __expf(d0 - mx), e1 = __expf(d1 - mx);
  float inv = 1.0f / (e0 + e1);
  float g0w = e0 * inv, g1w = e1 * inv;
  float xc[8];
  float s = 0.f, ss = 0.f;
  #pragma unroll
  for (int j = 0; j < 8; ++j) {
    xc[j] = xv[j] * g0w + cv[j] * g1w;
    s += xc[j]; ss += xc[j] * xc[j];
  }
  #pragma unroll
  for (int m = 1; m < 64; m <<= 1) { s += __shfl_xor(s, m); ss += __shfl_xor(ss, m); }
  float mu = s * (1.f / 512.f);
  float rstd = rsqrtf(ss * (1.f / 512.f) - mu * mu + 1e-5f);
  ushort o[8];
  #pragma unroll
  for (int j = 0; j < 8; ++j) {
    int e = lane * 8 + j;
    o[j] = f2bf((xc[j] - mu) * rstd * scale[e] + bias[e]);
  }
  *(s16x8*)(outb + row * 512 + lane * 8) = *(s16x8*)o;
}

extern "C" void kernel_launch(void* const* d_in, const int* in_sizes, int n_in,
                              void* d_out, int out_size, void* d_ws, size_t ws_size,
                              hipStream_t stream)
{
  (void)in_sizes; (void)n_in; (void)out_size; (void)ws_size;
  const int T = 4096, E = 512, HD = 2048;
  const float* body = (const float*)d_in[0];
  const float* limb = (const float*)d_in[1];
  const float* qw = (const float*)d_in[2];  const float* qb = (const float*)d_in[3];
  const float* kw = (const float*)d_in[4];  const float* kb = (const float*)d_in[5];
  const float* vw = (const float*)d_in[6];  const float* vb = (const float*)d_in[7];
  const float* ow = (const float*)d_in[8];  const float* ob = (const float*)d_in[9];
  const float* w1 = (const float*)d_in[10]; const float* fb1 = (const float*)d_in[11];
  const float* w2 = (const float*)d_in[12]; const float* fb2 = (const float*)d_in[13];
  const float* nsc = (const float*)d_in[14]; const float* nbi = (const float*)d_in[15];
  const float* gw = (const float*)d_in[16];  const float* gb = (const float*)d_in[17];
  const void* temp = d_in[18];

  char* ws = (char*)d_ws;
  size_t off = 0;
  auto alloc = [&](size_t b) { char* p = ws + off; off += (b + 255) & ~(size_t)255; return p; };
  ushort* FW    = (ushort*)alloc((size_t)4 * 1536 * 512 * 2);
  ushort* WOT   = (ushort*)alloc((size_t)4 * E * E * 2);
  ushort* W1T   = (ushort*)alloc((size_t)2 * E * HD * 2);
  ushort* W2T   = (ushort*)alloc((size_t)2 * HD * E * 2);
  ushort* XB    = (ushort*)alloc((size_t)T * E * 2);
  ushort* XL    = (ushort*)alloc((size_t)T * E * 2);
  float*  PROJ  = (float*)alloc((size_t)T * E * 4);
  ushort* BODYb = (ushort*)alloc((size_t)T * E * 2);
  ushort* LIMBb = (ushort*)alloc((size_t)T * E * 2);
  ushort* BCRb  = (ushort*)alloc((size_t)T * E * 2);
  ushort* LCRb  = (ushort*)alloc((size_t)T * E * 2);
  ushort* GBb   = (ushort*)alloc((size_t)T * E * 2);
  ushort* GLb   = (ushort*)alloc((size_t)T * E * 2);
  ushort* AOb   = (ushort*)alloc((size_t)T * E * 2);
  ushort* QA    = (ushort*)alloc((size_t)T * E * 2);
  ushort* KA    = (ushort*)alloc((size_t)T * E * 2);
  ushort* VTA   = (ushort*)alloc((size_t)T * E * 2);
  ushort* QB    = (ushort*)alloc((size_t)T * E * 2);
  ushort* KB    = (ushort*)alloc((size_t)T * E * 2);
  ushort* VTB   = (ushort*)alloc((size_t)T * E * 2);
  ushort* H1b   = QA;    // 16MB spans QA..QB region (dead by FFN time)
  float*  FFNf  = PROJ;  // reuse

  dim3 tb(32, 8);
  transpose_qkv<<<dim3(16, 16, 12), tb, 0, stream>>>(qw, kw, vw, FW);
  transpose_cvt<<<dim3(16, 16, 4), tb, 0, stream>>>(ow, WOT, E, E);
  transpose_cvt<<<dim3(64, 16, 2), tb, 0, stream>>>(w1, W1T, E, HD);
  transpose_cvt<<<dim3(16, 64, 2), tb, 0, stream>>>(w2, W2T, HD, E);
  cvt_bf16<<<T * E / 1024, 256, 0, stream>>>(body, XB, T * E);
  cvt_bf16<<<T * E / 1024, 256, 0, stream>>>(limb, XL, T * E);

  auto qkv = [&](const ushort* Aptr, int trip, ushort* qo, ushort* ko, ushort* vto) {
    GemmArgs a{};
    int qi = trip, kvi = trip ^ (trip >> 1);
    a.A = Aptr; a.Bt = FW + (size_t)trip * 1536 * 512;
    a.b0 = qb + qi * E; a.b1 = kb + kvi * E; a.b2 = vb + kvi * E;
    a.qo = qo; a.ko = ko; a.vto = vto; a.sp = temp;
    a.M = T; a.N = 1536; a.K = E; a.kind = 3;
    gemm_k<4, 4><<<dim3(12, 32), 256, 0, stream>>>(a);
  };
  auto oproj = [&](const ushort* Aptr, int i, float* of, ushort* obf, int kind) {
    GemmArgs a{};
    a.A = Aptr; a.Bt = WOT + (size_t)i * E * E;
    a.b0 = ob + i * E; a.outf = of; a.outb = obf;
    a.M = T; a.N = E; a.K = E; a.kind = kind;
    gemm_k<2, 4><<<dim3(4, 64), 256, 0, stream>>>(a);
  };

  // ---- self attention + residual LN
  qkv(XB, 0, QA, KA, VTA);
  attn_core<<<512, 256, 0, stream>>>(QA, KA, VTA, AOb);
  oproj(AOb, 0, PROJ, nullptr, 0);
  add_ln_ff<<<T / 4, 256, 0, stream>>>(body, PROJ, nsc + 0 * E, nbi + 0 * E, BODYb);

  qkv(XL, 1, QA, KA, VTA);
  attn_core<<<512, 256, 0, stream>>>(QA, KA, VTA, AOb);
  oproj(AOb, 1, PROJ, nullptr, 0);
  add_ln_ff<<<T / 4, 256, 0, stream>>>(limb, PROJ, nsc + 3 * E, nbi + 3 * E, LIMBb);

  // ---- cross attention
  qkv(BODYb, 2, QA, KA, VTA);   // q2(body), k3(body), v3(body)
  qkv(LIMBb, 3, QB, KB, VTB);   // q3(limb), k2(limb), v2(limb)
  attn_core<<<512, 256, 0, stream>>>(QA, KB, VTB, AOb);  // body2limb (attn 2)
  oproj(AOb, 2, nullptr, BCRb, 1);
  attn_core<<<512, 256, 0, stream>>>(QB, KA, VTA, AOb);  // limb2body (attn 3)
  oproj(AOb, 3, nullptr, LCRb, 1);

  // ---- gated merge + LN (norm index 1 for BOTH, faithful to reference)
  gate_ln_bb<<<T / 4, 256, 0, stream>>>(BODYb, BCRb, gw, gb, nsc + E, nbi + E, GBb);
  gate_ln_bb<<<T / 4, 256, 0, stream>>>(LIMBb, LCRb, gw, gb, nsc + E, nbi + E, GLb);

  // ---- FFN + residual LN -> final outputs
  for (int s = 0; s < 2; ++s) {
    const ushort* Xg = s ? GLb : GBb;
    int lni = s ? 5 : 2;
    GemmArgs a{};
    a.A = Xg; a.Bt = W1T + (size_t)s * HD * E; a.b0 = fb1 + s * HD;
    a.outb = H1b; a.M = T; a.N = HD; a.K = E; a.kind = 2;
    gemm_k<4, 4><<<dim3(16, 32), 256, 0, stream>>>(a);
    GemmArgs c{};
    c.A = H1b; c.Bt = W2T + (size_t)s * HD * E; c.b0 = fb2 + s * E;
    c.outf = FFNf; c.M = T; c.N = E; c.K = HD; c.kind = 0;
    gemm_k<2, 4><<<dim3(4, 64), 256, 0, stream>>>(c);
    add_ln_bf<<<T / 4, 256, 0, stream>>>(Xg, FFNf, nsc + lni * E, nbi + lni * E,
                                         (float*)d_out + (size_t)s * T * E);
  }
}

// Round 4
// 454.395 us; speedup vs baseline: 1.5222x; 1.4522x over previous
//
#include <hip/hip_runtime.h>

#define AS1 __attribute__((address_space(1)))
#define AS3 __attribute__((address_space(3)))

typedef __attribute__((ext_vector_type(4))) float f32x4;
typedef __attribute__((ext_vector_type(8))) short s16x8;

static __device__ __forceinline__ ushort f2bf(float f) {
  union { float f; unsigned u; } x; x.f = f;
  unsigned r = x.u + 0x7FFFu + ((x.u >> 16) & 1u);
  return (ushort)(r >> 16);
}
static __device__ __forceinline__ float bf2f(ushort u) {
  union { unsigned u; float f; } x; x.u = ((unsigned)u) << 16; return x.f;
}
static __device__ __forceinline__ float ex2(float x) {
  return __builtin_amdgcn_exp2f(x);
}
static __device__ __forceinline__ float parse_scalar(const void* p) {
  int i = *(const int*)p;
  if (i > 0 && i < 1000000) return (float)i;
  union { int i; float f; } u; u.i = i; return u.f;
}

// ---------------- one uber weight transpose+cvt kernel: f32 [K][N] -> bf16 [N][K]
// id<3072: fused QKV (FW[trip][1536][512]); 3072..4095: WOT; 4096..6143: W1T; else W2T
__global__ __launch_bounds__(256)
void transpose_all(const float* __restrict__ qw, const float* __restrict__ kw,
                   const float* __restrict__ vw, const float* __restrict__ ow,
                   const float* __restrict__ w1, const float* __restrict__ w2,
                   ushort* __restrict__ FW, ushort* __restrict__ WOT,
                   ushort* __restrict__ W1T, ushort* __restrict__ W2T)
{
  __shared__ float tile[32][33];
  int id = blockIdx.x;
  const float* in; ushort* out; int K, N, tx, ty;
  if (id < 3072) {
    int trip = id / 768, r = id - trip * 768, which = r >> 8, t2 = r & 255;
    int widx = (which == 0) ? trip : (trip ^ (trip >> 1));
    in = ((which == 0) ? qw : (which == 1) ? kw : vw) + (size_t)widx * 512 * 512;
    out = FW + (size_t)trip * 1536 * 512 + (size_t)which * 512 * 512;
    K = 512; N = 512; tx = t2 & 15; ty = t2 >> 4;
  } else if (id < 4096) {
    int r = id - 3072, wi = r >> 8, t2 = r & 255;
    in = ow + (size_t)wi * 512 * 512; out = WOT + (size_t)wi * 512 * 512;
    K = 512; N = 512; tx = t2 & 15; ty = t2 >> 4;
  } else if (id < 6144) {
    int r = id - 4096, s = r >> 10, t2 = r & 1023;
    in = w1 + (size_t)s * 512 * 2048; out = W1T + (size_t)s * 2048 * 512;
    K = 512; N = 2048; tx = t2 & 63; ty = t2 >> 6;
  } else {
    int r = id - 6144, s = r >> 10, t2 = r & 1023;
    in = w2 + (size_t)s * 2048 * 512; out = W2T + (size_t)s * 512 * 2048;
    K = 2048; N = 512; tx = t2 & 15; ty = t2 >> 4;
  }
  int nb = tx * 32, kb = ty * 32;
  int x = threadIdx.x, y = threadIdx.y;
  #pragma unroll
  for (int i = 0; i < 4; ++i)
    tile[y + i * 8][x] = in[(size_t)(kb + y + i * 8) * N + nb + x];
  __syncthreads();
  #pragma unroll
  for (int i = 0; i < 4; ++i)
    out[(size_t)(nb + y + i * 8) * K + kb + x] = f2bf(tile[x][y + i * 8]);
}

__global__ __launch_bounds__(256)
void cvt2_bf16(const float* __restrict__ a, const float* __restrict__ b,
               ushort* __restrict__ oa, ushort* __restrict__ ob)
{
  const float* in = blockIdx.y ? b : a;
  ushort* out = blockIdx.y ? ob : oa;
  int i = (blockIdx.x * 256 + threadIdx.x) * 4;
  float4 v = *(const float4*)(in + i);
  ushort4 o;
  o.x = f2bf(v.x); o.y = f2bf(v.y); o.z = f2bf(v.z); o.w = f2bf(v.w);
  *(ushort4*)(out + i) = o;
}

// ---------------- GEMM: C[M][N] = A[M][K](bf16) @ Bt[N][K](bf16) + bias
// kind: 0 f32 out, 1 bf16 out, 2 bf16+GELU out, 3 QKV split (q scaled, k plain, v transposed per-head)
struct GemmArgs {
  const ushort* A; const ushort* Bt;
  const float *b0, *b1, *b2;
  float* outf; ushort* outb;
  ushort *qo, *ko, *vto;
  const void* sp;
  int M, N, K, kind;
};

template<int FM, int FN>
__global__ __launch_bounds__(256)
void gemm_k(GemmArgs g0, GemmArgs g1)
{
  constexpr int BM = FM * 32, BN = FN * 32;
  __shared__ ushort As[2][BM * 64];
  __shared__ ushort Bs[2][BN * 64];
  GemmArgs g = blockIdx.z ? g1 : g0;
  const int t = threadIdx.x, lane = t & 63, w = t >> 6;
  const int lr = lane & 15, gq = lane >> 4;
  const int wr = w >> 1, wc = w & 1;
  const int m0 = blockIdx.y * BM, n0 = blockIdx.x * BN;
  const int K = g.K;
  const int nk = K >> 6;

  auto stage = [&](int kt, int buf) {
    #pragma unroll
    for (int p = 0; p < FM; ++p) {
      int c = p * 256 + t, row = c >> 3, sl = c & 7;
      const ushort* src = g.A + (size_t)(m0 + row) * K + kt * 64 + ((sl ^ (row & 7)) << 3);
      __builtin_amdgcn_global_load_lds((const AS1 void*)src,
          (AS3 void*)(As[buf] + (size_t)(p * 256 + (t & ~63)) * 8), 16, 0, 0);
    }
    #pragma unroll
    for (int p = 0; p < FN; ++p) {
      int c = p * 256 + t, row = c >> 3, sl = c & 7;
      const ushort* src = g.Bt + (size_t)(n0 + row) * K + kt * 64 + ((sl ^ (row & 7)) << 3);
      __builtin_amdgcn_global_load_lds((const AS1 void*)src,
          (AS3 void*)(Bs[buf] + (size_t)(p * 256 + (t & ~63)) * 8), 16, 0, 0);
    }
  };

  f32x4 acc[FM][FN];
  f32x4 zero = {0.f, 0.f, 0.f, 0.f};
  #pragma unroll
  for (int m = 0; m < FM; ++m)
    #pragma unroll
    for (int n = 0; n < FN; ++n) acc[m][n] = zero;

  stage(0, 0);
  __syncthreads();
  for (int kt = 0; kt < nk; ++kt) {
    int cur = kt & 1;
    const ushort* Ab = As[cur];
    const ushort* Bb = Bs[cur];
    if (kt + 1 < nk) stage(kt + 1, cur ^ 1);
    #pragma unroll
    for (int ks = 0; ks < 2; ++ks) {
      s16x8 af[FM], bfv[FN];
      #pragma unroll
      for (int m = 0; m < FM; ++m) {
        int row = wr * (FM * 16) + m * 16 + lr;
        af[m] = *(const s16x8*)(Ab + row * 64 + (((ks * 4 + gq) ^ (row & 7)) << 3));
      }
      #pragma unroll
      for (int n = 0; n < FN; ++n) {
        int row = wc * (FN * 16) + n * 16 + lr;
        bfv[n] = *(const s16x8*)(Bb + row * 64 + (((ks * 4 + gq) ^ (row & 7)) << 3));
      }
      __builtin_amdgcn_s_setprio(1);
      #pragma unroll
      for (int m = 0; m < FM; ++m)
        #pragma unroll
        for (int n = 0; n < FN; ++n)
          acc[m][n] = __builtin_amdgcn_mfma_f32_16x16x32_bf16(af[m], bfv[n], acc[m][n], 0, 0, 0);
      __builtin_amdgcn_s_setprio(0);
    }
    __syncthreads();
  }

  float qs = 1.0f;
  if (g.kind == 3 && g.sp) qs = 0.125f / parse_scalar(g.sp) * 1.4426950408889634f;
  #pragma unroll
  for (int n = 0; n < FN; ++n) {
    int col = n0 + wc * (FN * 16) + n * 16 + lr;
    int seg = col >> 9, cm = col & 511;
    float bv;
    if (g.kind == 3) bv = (seg == 0) ? g.b0[cm] : (seg == 1) ? g.b1[cm] : g.b2[cm];
    else bv = g.b0 ? g.b0[col] : 0.f;
    #pragma unroll
    for (int m = 0; m < FM; ++m) {
      int rowb = m0 + wr * (FM * 16) + m * 16 + 4 * gq;
      if (g.kind == 3) {
        if (seg == 2) {
          int d = cm & 63, hh = cm >> 6, bb = rowb >> 10, s = rowb & 1023;
          ushort4 pk;
          pk.x = f2bf(acc[m][n][0] + bv); pk.y = f2bf(acc[m][n][1] + bv);
          pk.z = f2bf(acc[m][n][2] + bv); pk.w = f2bf(acc[m][n][3] + bv);
          *(ushort4*)(g.vto + (((size_t)(bb * 8 + hh) * 64 + d) << 10) + s) = pk;
        } else if (seg == 1) {
          #pragma unroll
          for (int r = 0; r < 4; ++r)
            g.ko[(size_t)(rowb + r) * 512 + cm] = f2bf(acc[m][n][r] + bv);
        } else {
          #pragma unroll
          for (int r = 0; r < 4; ++r)
            g.qo[(size_t)(rowb + r) * 512 + cm] = f2bf((acc[m][n][r] + bv) * qs);
        }
      } else {
        #pragma unroll
        for (int r = 0; r < 4; ++r) {
          float v = acc[m][n][r] + bv;
          if (g.kind == 2) v = 0.5f * v * (1.0f + erff(v * 0.70710678118654752f));
          if (g.kind == 0) g.outf[(size_t)(rowb + r) * g.N + col] = v;
          else g.outb[(size_t)(rowb + r) * g.N + col] = f2bf(v);
        }
      }
    }
  }
}

// ---------------- flash attention core: LDS-staged K/V, double-buffered, prefetch,
// one barrier per tile. Q pre-scaled by 0.125/temp*log2e.
// Q,K: [B*1024][512]; VT: [B*H][64][1024]; O: [B*1024][512]. blockIdx.y selects stream.
__global__ __launch_bounds__(256)
void attn_core(const ushort* __restrict__ Q0, const ushort* __restrict__ K0,
               const ushort* __restrict__ V0, ushort* __restrict__ O0,
               const ushort* __restrict__ Q1, const ushort* __restrict__ K1,
               const ushort* __restrict__ V1, ushort* __restrict__ O1)
{
  __shared__ ushort Ks[2][64 * 64];
  __shared__ ushort Vs[2][64 * 64];
  __shared__ ushort Ps[4][1024];
  const int str = blockIdx.y;
  const ushort* Q = str ? Q1 : Q0;
  const ushort* Kx = str ? K1 : K0;
  const ushort* VT = str ? V1 : V0;
  ushort* O = str ? O1 : O0;

  const int t = threadIdx.x, lane = t & 63, w = t >> 6;
  const int lr = lane & 15, g = lane >> 4;
  int bid = blockIdx.x;
  int L = (bid & 7) * 64 + (bid >> 3);       // XCD-grouping swizzle
  int bh = L >> 4, qt = L & 15;
  size_t tbase = ((size_t)(bh >> 3) << 19) + ((size_t)(bh & 7) << 6);
  const ushort* Kbase = Kx + tbase;
  const ushort* Vbase = VT + ((size_t)bh << 16);
  int q0 = qt * 64 + w * 16;
  ushort* myPs = Ps[w];

  auto stage = [&](int kt, int buf) {
    #pragma unroll
    for (int p = 0; p < 2; ++p) {
      int c = p * 256 + t, row = c >> 3, sl = c & 7;
      const ushort* src = Kbase + (size_t)(kt * 64 + row) * 512 + ((sl ^ (row & 7)) << 3);
      __builtin_amdgcn_global_load_lds((const AS1 void*)src,
          (AS3 void*)(Ks[buf] + (size_t)(p * 256 + (t & ~63)) * 8), 16, 0, 0);
    }
    #pragma unroll
    for (int p = 0; p < 2; ++p) {
      int c = p * 256 + t, row = c >> 3, sl = c & 7;
      const ushort* src = Vbase + (size_t)row * 1024 + kt * 64 + ((sl ^ (row & 7)) << 3);
      __builtin_amdgcn_global_load_lds((const AS1 void*)src,
          (AS3 void*)(Vs[buf] + (size_t)(p * 256 + (t & ~63)) * 8), 16, 0, 0);
    }
  };

  s16x8 qf[2];
  #pragma unroll
  for (int ks = 0; ks < 2; ++ks)
    qf[ks] = *(const s16x8*)(Q + tbase + (size_t)(q0 + lr) * 512 + ks * 32 + g * 8);

  f32x4 po[4];
  f32x4 zero = {0.f, 0.f, 0.f, 0.f};
  #pragma unroll
  for (int dt = 0; dt < 4; ++dt) po[dt] = zero;
  float mrow[4] = {-1e30f, -1e30f, -1e30f, -1e30f};
  float lsum[4] = {0.f, 0.f, 0.f, 0.f};

  stage(0, 0);
  __syncthreads();
  #pragma unroll 2
  for (int kt = 0; kt < 16; ++kt) {
    int cur = kt & 1;
    const ushort* Kb = Ks[cur];
    const ushort* Vb = Vs[cur];
    if (kt < 15) stage(kt + 1, cur ^ 1);

    f32x4 sc[4];
    #pragma unroll
    for (int c = 0; c < 4; ++c) {
      sc[c] = zero;
      #pragma unroll
      for (int ks = 0; ks < 2; ++ks) {
        int row = c * 16 + lr;
        s16x8 kf = *(const s16x8*)(Kb + row * 64 + (((ks * 4 + g) ^ (row & 7)) << 3));
        sc[c] = __builtin_amdgcn_mfma_f32_16x16x32_bf16(qf[ks], kf, sc[c], 0, 0, 0);
      }
    }

    #pragma unroll
    for (int r = 0; r < 4; ++r) {
      float tm = fmaxf(fmaxf(sc[0][r], sc[1][r]), fmaxf(sc[2][r], sc[3][r]));
      #pragma unroll
      for (int msk = 1; msk < 16; msk <<= 1) tm = fmaxf(tm, __shfl_xor(tm, msk));
      float nm = fmaxf(mrow[r], tm);
      float fr = ex2(mrow[r] - nm);
      float ps = 0.f;
      #pragma unroll
      for (int c = 0; c < 4; ++c) {
        float pv = ex2(sc[c][r] - nm);
        sc[c][r] = pv;
        ps += pv;
      }
      #pragma unroll
      for (int msk = 1; msk < 16; msk <<= 1) ps += __shfl_xor(ps, msk);
      lsum[r] = lsum[r] * fr + ps;
      mrow[r] = nm;
      #pragma unroll
      for (int dt = 0; dt < 4; ++dt) po[dt][r] *= fr;
    }

    #pragma unroll
    for (int c = 0; c < 4; ++c)
      #pragma unroll
      for (int r = 0; r < 4; ++r) {
        int qq = 4 * g + r;
        int pa = (qq * 128 + (c * 16 + lr) * 2) ^ ((qq & 7) << 4);
        *(ushort*)((char*)myPs + pa) = f2bf(sc[c][r]);
      }
    s16x8 paf[2];
    #pragma unroll
    for (int ks = 0; ks < 2; ++ks)
      paf[ks] = *(const s16x8*)((char*)myPs + ((lr * 128 + ks * 64 + g * 16) ^ ((lr & 7) << 4)));
    __builtin_amdgcn_s_setprio(1);
    #pragma unroll
    for (int dt = 0; dt < 4; ++dt) {
      int vrow0 = dt * 16 + lr;
      #pragma unroll
      for (int ks = 0; ks < 2; ++ks) {
        s16x8 vf = *(const s16x8*)(Vb + vrow0 * 64 + (((ks * 4 + g) ^ (vrow0 & 7)) << 3));
        po[dt] = __builtin_amdgcn_mfma_f32_16x16x32_bf16(paf[ks], vf, po[dt], 0, 0, 0);
      }
    }
    __builtin_amdgcn_s_setprio(0);
    __syncthreads();
  }

  #pragma unroll
  for (int r = 0; r < 4; ++r) {
    float inv = 1.0f / lsum[r];
    #pragma unroll
    for (int dt = 0; dt < 4; ++dt)
      O[tbase + (size_t)(q0 + 4 * g + r) * 512 + dt * 16 + lr] = f2bf(po[dt][r] * inv);
  }
}

// ---------------- LN(a_f32 + b_f32) -> bf16, batched pair via blockIdx.y
__global__ __launch_bounds__(256)
void add_ln_ff2(const float* __restrict__ a0, const float* __restrict__ b0,
                ushort* __restrict__ o0, const float* __restrict__ a1,
                const float* __restrict__ b1, ushort* __restrict__ o1,
                const float* __restrict__ nsc, const float* __restrict__ nbi,
                int i0, int i1)
{
  const float* a = blockIdx.y ? a1 : a0;
  const float* b = blockIdx.y ? b1 : b0;
  ushort* outb = blockIdx.y ? o1 : o0;
  const float* scale = nsc + (blockIdx.y ? i1 : i0) * 512;
  const float* bias = nbi + (blockIdx.y ? i1 : i0) * 512;
  const int lane = threadIdx.x & 63, w = threadIdx.x >> 6;
  const size_t row = blockIdx.x * 4 + w;
  float x[8];
  #pragma unroll
  for (int j = 0; j < 8; j += 4) {
    float4 av = *(const float4*)(a + row * 512 + lane * 8 + j);
    float4 bv = *(const float4*)(b + row * 512 + lane * 8 + j);
    x[j] = av.x + bv.x; x[j + 1] = av.y + bv.y;
    x[j + 2] = av.z + bv.z; x[j + 3] = av.w + bv.w;
  }
  float s = 0.f, ss = 0.f;
  #pragma unroll
  for (int j = 0; j < 8; ++j) { s += x[j]; ss += x[j] * x[j]; }
  #pragma unroll
  for (int m = 1; m < 64; m <<= 1) { s += __shfl_xor(s, m); ss += __shfl_xor(ss, m); }
  float mu = s * (1.f / 512.f);
  float rstd = rsqrtf(ss * (1.f / 512.f) - mu * mu + 1e-5f);
  ushort o[8];
  #pragma unroll
  for (int j = 0; j < 8; ++j) {
    int e = lane * 8 + j;
    o[j] = f2bf((x[j] - mu) * rstd * scale[e] + bias[e]);
  }
  *(s16x8*)(outb + row * 512 + lane * 8) = *(s16x8*)o;
}

// ---------------- LN(a_bf16 + b_f32) -> f32 final, batched pair
__global__ __launch_bounds__(256)
void add_ln_bf2(const ushort* __restrict__ a0, const float* __restrict__ b0,
                float* __restrict__ o0, const ushort* __restrict__ a1,
                const float* __restrict__ b1, float* __restrict__ o1,
                const float* __restrict__ nsc, const float* __restrict__ nbi,
                int i0, int i1)
{
  const ushort* a = blockIdx.y ? a1 : a0;
  const float* b = blockIdx.y ? b1 : b0;
  float* outf = blockIdx.y ? o1 : o0;
  const float* scale = nsc + (blockIdx.y ? i1 : i0) * 512;
  const float* bias = nbi + (blockIdx.y ? i1 : i0) * 512;
  const int lane = threadIdx.x & 63, w = threadIdx.x >> 6;
  const size_t row = blockIdx.x * 4 + w;
  s16x8 av = *(const s16x8*)(a + row * 512 + lane * 8);
  float x[8];
  #pragma unroll
  for (int j = 0; j < 8; j += 4) {
    float4 bv = *(const float4*)(b + row * 512 + lane * 8 + j);
    x[j] = bf2f((ushort)av[j]) + bv.x; x[j + 1] = bf2f((ushort)av[j + 1]) + bv.y;
    x[j + 2] = bf2f((ushort)av[j + 2]) + bv.z; x[j + 3] = bf2f((ushort)av[j + 3]) + bv.w;
  }
  float s = 0.f, ss = 0.f;
  #pragma unroll
  for (int j = 0; j < 8; ++j) { s += x[j]; ss += x[j] * x[j]; }
  #pragma unroll
  for (int m = 1; m < 64; m <<= 1) { s += __shfl_xor(s, m); ss += __shfl_xor(ss, m); }
  float mu = s * (1.f / 512.f);
  float rstd = rsqrtf(ss * (1.f / 512.f) - mu * mu + 1e-5f);
  float o[8];
  #pragma unroll
  for (int j = 0; j < 8; ++j) {
    int e = lane * 8 + j;
    o[j] = (x[j] - mu) * rstd * scale[e] + bias[e];
  }
  *(float4*)(outf + row * 512 + lane * 8) = *(float4*)o;
  *(float4*)(outf + row * 512 + lane * 8 + 4) = *(float4*)(o + 4);
}

// ---------------- gated merge + LN, bf16 in/out, batched pair
__global__ __launch_bounds__(256)
void gate_ln2(const ushort* __restrict__ x0, const ushort* __restrict__ c0,
              ushort* __restrict__ o0, const ushort* __restrict__ x1,
              const ushort* __restrict__ c1, ushort* __restrict__ o1,
              const float* __restrict__ gw, const float* __restrict__ gb,
              const float* __restrict__ scale, const float* __restrict__ bias)
{
  const ushort* x = blockIdx.y ? x1 : x0;
  const ushort* cr = blockIdx.y ? c1 : c0;
  ushort* outb = blockIdx.y ? o1 : o0;
  const int lane = threadIdx.x & 63, w = threadIdx.x >> 6;
  const size_t row = blockIdx.x * 4 + w;
  s16x8 xv8 = *(const s16x8*)(x + row * 512 + lane * 8);
  s16x8 cv8 = *(const s16x8*)(cr + row * 512 + lane * 8);
  float xv[8], cv[8];
  #pragma unroll
  for (int j = 0; j < 8; ++j) { xv[j] = bf2f((ushort)xv8[j]); cv[j] = bf2f((ushort)cv8[j]); }
  float d0 = 0.f, d1 = 0.f;
  #pragma unroll
  for (int j = 0; j < 8; ++j) {
    int e = lane * 8 + j;
    float2 g0 = *(const float2*)(gw + 2 * e);
    float2 g1 = *(const float2*)(gw + 2 * (512 + e));
    d0 += xv[j] * g0.x + cv[j] * g1.x;
    d1 += xv[j] * g0.y + cv[j] * g1.y;
  }
  #pragma unroll
  for (int m = 1; m < 64; m <<= 1) { d0 += __shfl_xor(d0, m); d1 += __shfl_xor(d1, m); }
  d0 += gb[0]; d1 += gb[1];
  float mx = fmaxf(d0, d1);
  float e0 = __expf(d0 - mx), e1 = __expf(d1 - mx);
  float inv = 1.0f / (e0 + e1);
  float g0w = e0 * inv, g1w = e1 * inv;
  float xc[8];
  float s = 0.f, ss = 0.f;
  #pragma unroll
  for (int j = 0; j < 8; ++j) {
    xc[j] = xv[j] * g0w + cv[j] * g1w;
    s += xc[j]; ss += xc[j] * xc[j];
  }
  #pragma unroll
  for (int m = 1; m < 64; m <<= 1) { s += __shfl_xor(s, m); ss += __shfl_xor(ss, m); }
  float mu = s * (1.f / 512.f);
  float rstd = rsqrtf(ss * (1.f / 512.f) - mu * mu + 1e-5f);
  ushort o[8];
  #pragma unroll
  for (int j = 0; j < 8; ++j) {
    int e = lane * 8 + j;
    o[j] = f2bf((xc[j] - mu) * rstd * scale[e] + bias[e]);
  }
  *(s16x8*)(outb + row * 512 + lane * 8) = *(s16x8*)o;
}

extern "C" void kernel_launch(void* const* d_in, const int* in_sizes, int n_in,
                              void* d_out, int out_size, void* d_ws, size_t ws_size,
                              hipStream_t stream)
{
  (void)in_sizes; (void)n_in; (void)out_size; (void)ws_size;
  const int T = 4096, E = 512, HD = 2048;
  const float* body = (const float*)d_in[0];
  const float* limb = (const float*)d_in[1];
  const float* qw = (const float*)d_in[2];  const float* qb = (const float*)d_in[3];
  const float* kw = (const float*)d_in[4];  const float* kb = (const float*)d_in[5];
  const float* vw = (const float*)d_in[6];  const float* vb = (const float*)d_in[7];
  const float* ow = (const float*)d_in[8];  const float* ob = (const float*)d_in[9];
  const float* w1 = (const float*)d_in[10]; const float* fb1 = (const float*)d_in[11];
  const float* w2 = (const float*)d_in[12]; const float* fb2 = (const float*)d_in[13];
  const float* nsc = (const float*)d_in[14]; const float* nbi = (const float*)d_in[15];
  const float* gw = (const float*)d_in[16];  const float* gb = (const float*)d_in[17];
  const void* temp = d_in[18];

  char* ws = (char*)d_ws;
  size_t off = 0;
  auto alloc = [&](size_t b) { char* p = ws + off; off += (b + 255) & ~(size_t)255; return p; };
  ushort* FW    = (ushort*)alloc((size_t)4 * 1536 * 512 * 2);
  ushort* WOT   = (ushort*)alloc((size_t)4 * E * E * 2);
  ushort* W1T   = (ushort*)alloc((size_t)2 * E * HD * 2);
  ushort* W2T   = (ushort*)alloc((size_t)2 * HD * E * 2);
  ushort* XB    = (ushort*)alloc((size_t)T * E * 2);
  ushort* XL    = (ushort*)alloc((size_t)T * E * 2);
  float*  PROJA = (float*)alloc((size_t)T * E * 4);
  float*  PROJB = (float*)alloc((size_t)T * E * 4);
  ushort* BODYb = (ushort*)alloc((size_t)T * E * 2);
  ushort* LIMBb = (ushort*)alloc((size_t)T * E * 2);
  ushort* BCRb  = (ushort*)alloc((size_t)T * E * 2);
  ushort* LCRb  = (ushort*)alloc((size_t)T * E * 2);
  ushort* GBb   = (ushort*)alloc((size_t)T * E * 2);
  ushort* GLb   = (ushort*)alloc((size_t)T * E * 2);
  ushort* QA    = (ushort*)alloc((size_t)T * E * 2);
  ushort* KA    = (ushort*)alloc((size_t)T * E * 2);
  ushort* VTA   = (ushort*)alloc((size_t)T * E * 2);
  ushort* QB    = (ushort*)alloc((size_t)T * E * 2);
  ushort* KB    = (ushort*)alloc((size_t)T * E * 2);
  ushort* VTB   = (ushort*)alloc((size_t)T * E * 2);
  ushort* AOA   = (ushort*)alloc((size_t)T * E * 2);
  ushort* AOB   = (ushort*)alloc((size_t)T * E * 2);
  ushort* H1A   = QA;     // 16 MB spans QA,KA,VTA,QB (dead by FFN)
  ushort* H1B   = KB;     // 16 MB spans KB,VTB,AOA,AOB (dead by FFN)
  float*  FFNA  = PROJA;  // reuse
  float*  FFNB  = PROJB;  // reuse

  transpose_all<<<8192, dim3(32, 8), 0, stream>>>(qw, kw, vw, ow, w1, w2, FW, WOT, W1T, W2T);
  cvt2_bf16<<<dim3(T * E / 1024, 2), 256, 0, stream>>>(body, limb, XB, XL);

  auto qkv_pair = [&](const ushort* A0, int t0, ushort* q0, ushort* k0, ushort* v0,
                      const ushort* A1, int t1, ushort* q1, ushort* k1, ushort* v1) {
    GemmArgs a{}, b{};
    int kv0 = t0 ^ (t0 >> 1), kv1 = t1 ^ (t1 >> 1);
    a.A = A0; a.Bt = FW + (size_t)t0 * 1536 * 512;
    a.b0 = qb + t0 * E; a.b1 = kb + kv0 * E; a.b2 = vb + kv0 * E;
    a.qo = q0; a.ko = k0; a.vto = v0; a.sp = temp; a.M = T; a.N = 1536; a.K = E; a.kind = 3;
    b = a;
    b.A = A1; b.Bt = FW + (size_t)t1 * 1536 * 512;
    b.b0 = qb + t1 * E; b.b1 = kb + kv1 * E; b.b2 = vb + kv1 * E;
    b.qo = q1; b.ko = k1; b.vto = v1;
    gemm_k<4, 4><<<dim3(12, 32, 2), 256, 0, stream>>>(a, b);
  };
  auto oproj_pair = [&](const ushort* A0, int i0, float* of0, ushort* ob0,
                        const ushort* A1, int i1, float* of1, ushort* ob1, int kind) {
    GemmArgs a{}, b{};
    a.A = A0; a.Bt = WOT + (size_t)i0 * E * E; a.b0 = ob + i0 * E;
    a.outf = of0; a.outb = ob0; a.M = T; a.N = E; a.K = E; a.kind = kind;
    b = a;
    b.A = A1; b.Bt = WOT + (size_t)i1 * E * E; b.b0 = ob + i1 * E;
    b.outf = of1; b.outb = ob1;
    gemm_k<2, 4><<<dim3(4, 64, 2), 256, 0, stream>>>(a, b);
  };

  // ---- self attention (both streams batched)
  qkv_pair(XB, 0, QA, KA, VTA, XL, 1, QB, KB, VTB);
  attn_core<<<dim3(512, 2), 256, 0, stream>>>(QA, KA, VTA, AOA, QB, KB, VTB, AOB);
  oproj_pair(AOA, 0, PROJA, nullptr, AOB, 1, PROJB, nullptr, 0);
  add_ln_ff2<<<dim3(T / 4, 2), 256, 0, stream>>>(body, PROJA, BODYb, limb, PROJB, LIMBb,
                                                 nsc, nbi, 0, 3);
  // ---- cross attention
  qkv_pair(BODYb, 2, QA, KA, VTA, LIMBb, 3, QB, KB, VTB);
  attn_core<<<dim3(512, 2), 256, 0, stream>>>(QA, KB, VTB, AOA, QB, KA, VTA, AOB);
  oproj_pair(AOA, 2, nullptr, BCRb, AOB, 3, nullptr, LCRb, 1);

  // ---- gated merge + LN (norm index 1 for BOTH, faithful to reference)
  gate_ln2<<<dim3(T / 4, 2), 256, 0, stream>>>(BODYb, BCRb, GBb, LIMBb, LCRb, GLb,
                                               gw, gb, nsc + E, nbi + E);

  // ---- FFN + residual LN -> final outputs
  {
    GemmArgs a{}, b{};
    a.A = GBb; a.Bt = W1T; a.b0 = fb1; a.outb = H1A;
    a.M = T; a.N = HD; a.K = E; a.kind = 2;
    b = a; b.A = GLb; b.Bt = W1T + (size_t)HD * E; b.b0 = fb1 + HD; b.outb = H1B;
    gemm_k<4, 4><<<dim3(16, 32, 2), 256, 0, stream>>>(a, b);
  }
  {
    GemmArgs a{}, b{};
    a.A = H1A; a.Bt = W2T; a.b0 = fb2; a.outf = FFNA;
    a.M = T; a.N = E; a.K = HD; a.kind = 0;
    b = a; b.A = H1B; b.Bt = W2T + (size_t)HD * E; b.b0 = fb2 + E; b.outf = FFNB;
    gemm_k<2, 4><<<dim3(4, 64, 2), 256, 0, stream>>>(a, b);
  }
  add_ln_bf2<<<dim3(T / 4, 2), 256, 0, stream>>>(GBb, FFNA, (float*)d_out,
                                                 GLb, FFNB, (float*)d_out + (size_t)T * E,
                                                 nsc, nbi, 2, 5);
}

// Round 5
// 404.050 us; speedup vs baseline: 1.7119x; 1.1246x over previous
//
#include <hip/hip_runtime.h>

#define AS1 __attribute__((address_space(1)))
#define AS3 __attribute__((address_space(3)))

typedef __attribute__((ext_vector_type(4))) float f32x4;
typedef __attribute__((ext_vector_type(8))) short s16x8;

static __device__ __forceinline__ ushort f2bf(float f) {
  union { float f; unsigned u; } x; x.f = f;
  unsigned r = x.u + 0x7FFFu + ((x.u >> 16) & 1u);
  return (ushort)(r >> 16);
}
static __device__ __forceinline__ float bf2f(ushort u) {
  union { unsigned u; float f; } x; x.u = ((unsigned)u) << 16; return x.f;
}
static __device__ __forceinline__ float ex2(float x) {
  return __builtin_amdgcn_exp2f(x);
}
static __device__ __forceinline__ unsigned cvt_pk_bf16(float a, float b) {
  unsigned r;
  asm("v_cvt_pk_bf16_f32 %0, %1, %2" : "=v"(r) : "v"(a), "v"(b));
  return r;
}
static __device__ __forceinline__ float parse_scalar(const void* p) {
  int i = *(const int*)p;
  if (i > 0 && i < 1000000) return (float)i;
  union { int i; float f; } u; u.i = i; return u.f;
}

// ---------------- one uber weight transpose+cvt kernel: f32 [K][N] -> bf16 [N][K]
__global__ __launch_bounds__(256)
void transpose_all(const float* __restrict__ qw, const float* __restrict__ kw,
                   const float* __restrict__ vw, const float* __restrict__ ow,
                   const float* __restrict__ w1, const float* __restrict__ w2,
                   ushort* __restrict__ FW, ushort* __restrict__ WOT,
                   ushort* __restrict__ W1T, ushort* __restrict__ W2T)
{
  __shared__ float tile[32][33];
  int id = blockIdx.x;
  const float* in; ushort* out; int K, N, tx, ty;
  if (id < 3072) {
    int trip = id / 768, r = id - trip * 768, which = r >> 8, t2 = r & 255;
    int widx = (which == 0) ? trip : (trip ^ (trip >> 1));
    in = ((which == 0) ? qw : (which == 1) ? kw : vw) + (size_t)widx * 512 * 512;
    out = FW + (size_t)trip * 1536 * 512 + (size_t)which * 512 * 512;
    K = 512; N = 512; tx = t2 & 15; ty = t2 >> 4;
  } else if (id < 4096) {
    int r = id - 3072, wi = r >> 8, t2 = r & 255;
    in = ow + (size_t)wi * 512 * 512; out = WOT + (size_t)wi * 512 * 512;
    K = 512; N = 512; tx = t2 & 15; ty = t2 >> 4;
  } else if (id < 6144) {
    int r = id - 4096, s = r >> 10, t2 = r & 1023;
    in = w1 + (size_t)s * 512 * 2048; out = W1T + (size_t)s * 2048 * 512;
    K = 512; N = 2048; tx = t2 & 63; ty = t2 >> 6;
  } else {
    int r = id - 6144, s = r >> 10, t2 = r & 1023;
    in = w2 + (size_t)s * 2048 * 512; out = W2T + (size_t)s * 512 * 2048;
    K = 2048; N = 512; tx = t2 & 15; ty = t2 >> 4;
  }
  int nb = tx * 32, kb = ty * 32;
  int x = threadIdx.x, y = threadIdx.y;
  #pragma unroll
  for (int i = 0; i < 4; ++i)
    tile[y + i * 8][x] = in[(size_t)(kb + y + i * 8) * N + nb + x];
  __syncthreads();
  #pragma unroll
  for (int i = 0; i < 4; ++i)
    out[(size_t)(nb + y + i * 8) * K + kb + x] = f2bf(tile[x][y + i * 8]);
}

__global__ __launch_bounds__(256)
void cvt2_bf16(const float* __restrict__ a, const float* __restrict__ b,
               ushort* __restrict__ oa, ushort* __restrict__ ob)
{
  const float* in = blockIdx.y ? b : a;
  ushort* out = blockIdx.y ? ob : oa;
  int i = (blockIdx.x * 256 + threadIdx.x) * 4;
  float4 v = *(const float4*)(in + i);
  ushort4 o;
  o.x = f2bf(v.x); o.y = f2bf(v.y); o.z = f2bf(v.z); o.w = f2bf(v.w);
  *(ushort4*)(out + i) = o;
}

// ---------------- GEMM: C[M][N] = A[M][K](bf16) @ Bt[N][K](bf16) + bias
// kind: 0 f32 out, 1 bf16 out, 2 bf16+GELU out, 3 QKV split (q scaled, k plain, v transposed per-head)
struct GemmArgs {
  const ushort* A; const ushort* Bt;
  const float *b0, *b1, *b2;
  float* outf; ushort* outb;
  ushort *qo, *ko, *vto;
  const void* sp;
  int M, N, K, kind;
};

template<int FM, int FN>
__global__ __launch_bounds__(256)
void gemm_k(GemmArgs g0, GemmArgs g1)
{
  constexpr int BM = FM * 32, BN = FN * 32;
  __shared__ ushort As[2][BM * 64];
  __shared__ ushort Bs[2][BN * 64];
  GemmArgs g = blockIdx.z ? g1 : g0;
  const int t = threadIdx.x, lane = t & 63, w = t >> 6;
  const int lr = lane & 15, gq = lane >> 4;
  const int wr = w >> 1, wc = w & 1;
  const int m0 = blockIdx.y * BM, n0 = blockIdx.x * BN;
  const int K = g.K;
  const int nk = K >> 6;

  auto stage = [&](int kt, int buf) {
    #pragma unroll
    for (int p = 0; p < FM; ++p) {
      int c = p * 256 + t, row = c >> 3, sl = c & 7;
      const ushort* src = g.A + (size_t)(m0 + row) * K + kt * 64 + ((sl ^ (row & 7)) << 3);
      __builtin_amdgcn_global_load_lds((const AS1 void*)src,
          (AS3 void*)(As[buf] + (size_t)(p * 256 + (t & ~63)) * 8), 16, 0, 0);
    }
    #pragma unroll
    for (int p = 0; p < FN; ++p) {
      int c = p * 256 + t, row = c >> 3, sl = c & 7;
      const ushort* src = g.Bt + (size_t)(n0 + row) * K + kt * 64 + ((sl ^ (row & 7)) << 3);
      __builtin_amdgcn_global_load_lds((const AS1 void*)src,
          (AS3 void*)(Bs[buf] + (size_t)(p * 256 + (t & ~63)) * 8), 16, 0, 0);
    }
  };

  f32x4 acc[FM][FN];
  f32x4 zero = {0.f, 0.f, 0.f, 0.f};
  #pragma unroll
  for (int m = 0; m < FM; ++m)
    #pragma unroll
    for (int n = 0; n < FN; ++n) acc[m][n] = zero;

  stage(0, 0);
  __syncthreads();
  for (int kt = 0; kt < nk; ++kt) {
    int cur = kt & 1;
    const ushort* Ab = As[cur];
    const ushort* Bb = Bs[cur];
    if (kt + 1 < nk) stage(kt + 1, cur ^ 1);
    #pragma unroll
    for (int ks = 0; ks < 2; ++ks) {
      s16x8 af[FM], bfv[FN];
      #pragma unroll
      for (int m = 0; m < FM; ++m) {
        int row = wr * (FM * 16) + m * 16 + lr;
        af[m] = *(const s16x8*)(Ab + row * 64 + (((ks * 4 + gq) ^ (row & 7)) << 3));
      }
      #pragma unroll
      for (int n = 0; n < FN; ++n) {
        int row = wc * (FN * 16) + n * 16 + lr;
        bfv[n] = *(const s16x8*)(Bb + row * 64 + (((ks * 4 + gq) ^ (row & 7)) << 3));
      }
      __builtin_amdgcn_s_setprio(1);
      #pragma unroll
      for (int m = 0; m < FM; ++m)
        #pragma unroll
        for (int n = 0; n < FN; ++n)
          acc[m][n] = __builtin_amdgcn_mfma_f32_16x16x32_bf16(af[m], bfv[n], acc[m][n], 0, 0, 0);
      __builtin_amdgcn_s_setprio(0);
    }
    __syncthreads();
  }

  float qs = 1.0f;
  if (g.kind == 3 && g.sp) qs = 0.125f / parse_scalar(g.sp) * 1.4426950408889634f;
  #pragma unroll
  for (int n = 0; n < FN; ++n) {
    int col = n0 + wc * (FN * 16) + n * 16 + lr;
    int seg = col >> 9, cm = col & 511;
    float bv;
    if (g.kind == 3) bv = (seg == 0) ? g.b0[cm] : (seg == 1) ? g.b1[cm] : g.b2[cm];
    else bv = g.b0 ? g.b0[col] : 0.f;
    #pragma unroll
    for (int m = 0; m < FM; ++m) {
      int rowb = m0 + wr * (FM * 16) + m * 16 + 4 * gq;
      if (g.kind == 3) {
        if (seg == 2) {
          int d = cm & 63, hh = cm >> 6, bb = rowb >> 10, s = rowb & 1023;
          ushort4 pk;
          pk.x = f2bf(acc[m][n][0] + bv); pk.y = f2bf(acc[m][n][1] + bv);
          pk.z = f2bf(acc[m][n][2] + bv); pk.w = f2bf(acc[m][n][3] + bv);
          *(ushort4*)(g.vto + (((size_t)(bb * 8 + hh) * 64 + d) << 10) + s) = pk;
        } else if (seg == 1) {
          #pragma unroll
          for (int r = 0; r < 4; ++r)
            g.ko[(size_t)(rowb + r) * 512 + cm] = f2bf(acc[m][n][r] + bv);
        } else {
          #pragma unroll
          for (int r = 0; r < 4; ++r)
            g.qo[(size_t)(rowb + r) * 512 + cm] = f2bf((acc[m][n][r] + bv) * qs);
        }
      } else {
        #pragma unroll
        for (int r = 0; r < 4; ++r) {
          float v = acc[m][n][r] + bv;
          if (g.kind == 2) v = 0.5f * v * (1.0f + erff(v * 0.70710678118654752f));
          if (g.kind == 0) g.outf[(size_t)(rowb + r) * g.N + col] = v;
          else g.outb[(size_t)(rowb + r) * g.N + col] = f2bf(v);
        }
      }
    }
  }
}

// ---------------- flash attention core v3: double-swapped MFMA (lane-local softmax).
// QK^T computed as mfma(K,Q): lane holds S[key=16c+4g+r][q=lr] -> in-register row stats.
// PV computed as mfma(V,P): rescale factor per-lane scalar. LDS-staged K/V, double-buffered.
// Q pre-scaled by 0.125/temp*log2e. Q,K: [B*1024][512]; VT: [B*H][64][1024]; O: [B*1024][512].
__global__ __launch_bounds__(256)
void attn_core(const ushort* __restrict__ Q0, const ushort* __restrict__ K0,
               const ushort* __restrict__ V0, ushort* __restrict__ O0,
               const ushort* __restrict__ Q1, const ushort* __restrict__ K1,
               const ushort* __restrict__ V1, ushort* __restrict__ O1)
{
  __shared__ ushort Ks[2][64 * 64];
  __shared__ ushort Vs[2][64 * 64];
  __shared__ ushort Ps[4][1024];
  const int str = blockIdx.y;
  const ushort* Q = str ? Q1 : Q0;
  const ushort* Kx = str ? K1 : K0;
  const ushort* VT = str ? V1 : V0;
  ushort* O = str ? O1 : O0;

  const int t = threadIdx.x, lane = t & 63, w = t >> 6;
  const int lr = lane & 15, g = lane >> 4;
  int bid = blockIdx.x;
  int L = (bid & 7) * 64 + (bid >> 3);       // XCD-grouping swizzle
  int bh = L >> 4, qt = L & 15;
  size_t tbase = ((size_t)(bh >> 3) << 19) + ((size_t)(bh & 7) << 6);
  const ushort* Kbase = Kx + tbase;
  const ushort* Vbase = VT + ((size_t)bh << 16);
  int q0 = qt * 64 + w * 16;
  char* myPs = (char*)Ps[w];
  const int psw = (lr & 7) << 4;             // per-row LDS swizzle bits

  auto stage = [&](int kt, int buf) {
    #pragma unroll
    for (int p = 0; p < 2; ++p) {
      int c = p * 256 + t, row = c >> 3, sl = c & 7;
      const ushort* src = Kbase + (size_t)(kt * 64 + row) * 512 + ((sl ^ (row & 7)) << 3);
      __builtin_amdgcn_global_load_lds((const AS1 void*)src,
          (AS3 void*)(Ks[buf] + (size_t)(p * 256 + (t & ~63)) * 8), 16, 0, 0);
    }
    #pragma unroll
    for (int p = 0; p < 2; ++p) {
      int c = p * 256 + t, row = c >> 3, sl = c & 7;
      const ushort* src = Vbase + (size_t)row * 1024 + kt * 64 + ((sl ^ (row & 7)) << 3);
      __builtin_amdgcn_global_load_lds((const AS1 void*)src,
          (AS3 void*)(Vs[buf] + (size_t)(p * 256 + (t & ~63)) * 8), 16, 0, 0);
    }
  };

  s16x8 qf[2];
  #pragma unroll
  for (int ks = 0; ks < 2; ++ks)
    qf[ks] = *(const s16x8*)(Q + tbase + (size_t)(q0 + lr) * 512 + ks * 32 + g * 8);

  f32x4 po[4];
  f32x4 zero = {0.f, 0.f, 0.f, 0.f};
  #pragma unroll
  for (int dt = 0; dt < 4; ++dt) po[dt] = zero;
  float mrow = -1e30f, lsum = 0.f;

  stage(0, 0);
  __syncthreads();
  #pragma unroll 2
  for (int kt = 0; kt < 16; ++kt) {
    int cur = kt & 1;
    const ushort* Kb = Ks[cur];
    const ushort* Vb = Vs[cur];
    if (kt < 15) stage(kt + 1, cur ^ 1);

    // scores: lane holds S[key=16c+4g+r][q=lr]
    f32x4 sc[4];
    #pragma unroll
    for (int c = 0; c < 4; ++c) {
      sc[c] = zero;
      #pragma unroll
      for (int ks = 0; ks < 2; ++ks) {
        int row = c * 16 + lr;
        s16x8 kf = *(const s16x8*)(Kb + row * 64 + (((ks * 4 + g) ^ (row & 7)) << 3));
        sc[c] = __builtin_amdgcn_mfma_f32_16x16x32_bf16(kf, qf[ks], sc[c], 0, 0, 0);
      }
    }

    // per-lane online softmax for q = lr (keys split across 4 g-lanes)
    float tm = sc[0][0];
    #pragma unroll
    for (int c = 0; c < 4; ++c)
      #pragma unroll
      for (int r = 0; r < 4; ++r) tm = fmaxf(tm, sc[c][r]);
    tm = fmaxf(tm, __shfl_xor(tm, 16));
    tm = fmaxf(tm, __shfl_xor(tm, 32));
    float nm = fmaxf(mrow, tm);
    float fr = ex2(mrow - nm);
    float ts = 0.f;
    #pragma unroll
    for (int c = 0; c < 4; ++c)
      #pragma unroll
      for (int r = 0; r < 4; ++r) {
        float pv = ex2(sc[c][r] - nm);
        sc[c][r] = pv;
        ts += pv;
      }
    ts += __shfl_xor(ts, 16);
    ts += __shfl_xor(ts, 32);
    lsum = lsum * fr + ts;
    mrow = nm;
    #pragma unroll
    for (int dt = 0; dt < 4; ++dt) po[dt] *= fr;

    // P -> LDS: pack 4 keys (r=0..3) per b64 write; row q=lr
    #pragma unroll
    for (int c = 0; c < 4; ++c) {
      uint2 d;
      d.x = cvt_pk_bf16(sc[c][0], sc[c][1]);
      d.y = cvt_pk_bf16(sc[c][2], sc[c][3]);
      *(uint2*)(myPs + lr * 128 + ((c * 32 + g * 8) ^ psw)) = d;
    }
    s16x8 paf[2];
    #pragma unroll
    for (int ks = 0; ks < 2; ++ks)
      paf[ks] = *(const s16x8*)(myPs + lr * 128 + ((ks * 64 + g * 16) ^ psw));

    __builtin_amdgcn_s_setprio(1);
    #pragma unroll
    for (int dt = 0; dt < 4; ++dt) {
      int vrow = dt * 16 + lr;
      #pragma unroll
      for (int ks = 0; ks < 2; ++ks) {
        s16x8 vf = *(const s16x8*)(Vb + vrow * 64 + (((ks * 4 + g) ^ (vrow & 7)) << 3));
        po[dt] = __builtin_amdgcn_mfma_f32_16x16x32_bf16(vf, paf[ks], po[dt], 0, 0, 0);
      }
    }
    __builtin_amdgcn_s_setprio(0);
    __syncthreads();
  }

  // epilogue: lane holds O[d=dt*16+4g+r][q=lr]; write ushort4 per dt
  float inv = 1.0f / lsum;
  #pragma unroll
  for (int dt = 0; dt < 4; ++dt) {
    ushort4 pk;
    pk.x = f2bf(po[dt][0] * inv);
    pk.y = f2bf(po[dt][1] * inv);
    pk.z = f2bf(po[dt][2] * inv);
    pk.w = f2bf(po[dt][3] * inv);
    *(ushort4*)(O + tbase + (size_t)(q0 + lr) * 512 + dt * 16 + 4 * g) = pk;
  }
}

// ---------------- LN(a_f32 + b_f32) -> bf16, batched pair via blockIdx.y
__global__ __launch_bounds__(256)
void add_ln_ff2(const float* __restrict__ a0, const float* __restrict__ b0,
                ushort* __restrict__ o0, const float* __restrict__ a1,
                const float* __restrict__ b1, ushort* __restrict__ o1,
                const float* __restrict__ nsc, const float* __restrict__ nbi,
                int i0, int i1)
{
  const float* a = blockIdx.y ? a1 : a0;
  const float* b = blockIdx.y ? b1 : b0;
  ushort* outb = blockIdx.y ? o1 : o0;
  const float* scale = nsc + (blockIdx.y ? i1 : i0) * 512;
  const float* bias = nbi + (blockIdx.y ? i1 : i0) * 512;
  const int lane = threadIdx.x & 63, w = threadIdx.x >> 6;
  const size_t row = blockIdx.x * 4 + w;
  float x[8];
  #pragma unroll
  for (int j = 0; j < 8; j += 4) {
    float4 av = *(const float4*)(a + row * 512 + lane * 8 + j);
    float4 bv = *(const float4*)(b + row * 512 + lane * 8 + j);
    x[j] = av.x + bv.x; x[j + 1] = av.y + bv.y;
    x[j + 2] = av.z + bv.z; x[j + 3] = av.w + bv.w;
  }
  float s = 0.f, ss = 0.f;
  #pragma unroll
  for (int j = 0; j < 8; ++j) { s += x[j]; ss += x[j] * x[j]; }
  #pragma unroll
  for (int m = 1; m < 64; m <<= 1) { s += __shfl_xor(s, m); ss += __shfl_xor(ss, m); }
  float mu = s * (1.f / 512.f);
  float rstd = rsqrtf(ss * (1.f / 512.f) - mu * mu + 1e-5f);
  ushort o[8];
  #pragma unroll
  for (int j = 0; j < 8; ++j) {
    int e = lane * 8 + j;
    o[j] = f2bf((x[j] - mu) * rstd * scale[e] + bias[e]);
  }
  *(s16x8*)(outb + row * 512 + lane * 8) = *(s16x8*)o;
}

// ---------------- LN(a_bf16 + b_f32) -> f32 final, batched pair
__global__ __launch_bounds__(256)
void add_ln_bf2(const ushort* __restrict__ a0, const float* __restrict__ b0,
                float* __restrict__ o0, const ushort* __restrict__ a1,
                const float* __restrict__ b1, float* __restrict__ o1,
                const float* __restrict__ nsc, const float* __restrict__ nbi,
                int i0, int i1)
{
  const ushort* a = blockIdx.y ? a1 : a0;
  const float* b = blockIdx.y ? b1 : b0;
  float* outf = blockIdx.y ? o1 : o0;
  const float* scale = nsc + (blockIdx.y ? i1 : i0) * 512;
  const float* bias = nbi + (blockIdx.y ? i1 : i0) * 512;
  const int lane = threadIdx.x & 63, w = threadIdx.x >> 6;
  const size_t row = blockIdx.x * 4 + w;
  s16x8 av = *(const s16x8*)(a + row * 512 + lane * 8);
  float x[8];
  #pragma unroll
  for (int j = 0; j < 8; j += 4) {
    float4 bv = *(const float4*)(b + row * 512 + lane * 8 + j);
    x[j] = bf2f((ushort)av[j]) + bv.x; x[j + 1] = bf2f((ushort)av[j + 1]) + bv.y;
    x[j + 2] = bf2f((ushort)av[j + 2]) + bv.z; x[j + 3] = bf2f((ushort)av[j + 3]) + bv.w;
  }
  float s = 0.f, ss = 0.f;
  #pragma unroll
  for (int j = 0; j < 8; ++j) { s += x[j]; ss += x[j] * x[j]; }
  #pragma unroll
  for (int m = 1; m < 64; m <<= 1) { s += __shfl_xor(s, m); ss += __shfl_xor(ss, m); }
  float mu = s * (1.f / 512.f);
  float rstd = rsqrtf(ss * (1.f / 512.f) - mu * mu + 1e-5f);
  float o[8];
  #pragma unroll
  for (int j = 0; j < 8; ++j) {
    int e = lane * 8 + j;
    o[j] = (x[j] - mu) * rstd * scale[e] + bias[e];
  }
  *(float4*)(outf + row * 512 + lane * 8) = *(float4*)o;
  *(float4*)(outf + row * 512 + lane * 8 + 4) = *(float4*)(o + 4);
}

// ---------------- gated merge + LN, bf16 in/out, batched pair
__global__ __launch_bounds__(256)
void gate_ln2(const ushort* __restrict__ x0, const ushort* __restrict__ c0,
              ushort* __restrict__ o0, const ushort* __restrict__ x1,
              const ushort* __restrict__ c1, ushort* __restrict__ o1,
              const float* __restrict__ gw, const float* __restrict__ gb,
              const float* __restrict__ scale, const float* __restrict__ bias)
{
  const ushort* x = blockIdx.y ? x1 : x0;
  const ushort* cr = blockIdx.y ? c1 : c0;
  ushort* outb = blockIdx.y ? o1 : o0;
  const int lane = threadIdx.x & 63, w = threadIdx.x >> 6;
  const size_t row = blockIdx.x * 4 + w;
  s16x8 xv8 = *(const s16x8*)(x + row * 512 + lane * 8);
  s16x8 cv8 = *(const s16x8*)(cr + row * 512 + lane * 8);
  float xv[8], cv[8];
  #pragma unroll
  for (int j = 0; j < 8; ++j) { xv[j] = bf2f((ushort)xv8[j]); cv[j] = bf2f((ushort)cv8[j]); }
  float d0 = 0.f, d1 = 0.f;
  #pragma unroll
  for (int j = 0; j < 8; ++j) {
    int e = lane * 8 + j;
    float2 g0 = *(const float2*)(gw + 2 * e);
    float2 g1 = *(const float2*)(gw + 2 * (512 + e));
    d0 += xv[j] * g0.x + cv[j] * g1.x;
    d1 += xv[j] * g0.y + cv[j] * g1.y;
  }
  #pragma unroll
  for (int m = 1; m < 64; m <<= 1) { d0 += __shfl_xor(d0, m); d1 += __shfl_xor(d1, m); }
  d0 += gb[0]; d1 += gb[1];
  float mx = fmaxf(d0, d1);
  float e0 = __expf(d0 - mx), e1 = __expf(d1 - mx);
  float inv = 1.0f / (e0 + e1);
  float g0w = e0 * inv, g1w = e1 * inv;
  float xc[8];
  float s = 0.f, ss = 0.f;
  #pragma unroll
  for (int j = 0; j < 8; ++j) {
    xc[j] = xv[j] * g0w + cv[j] * g1w;
    s += xc[j]; ss += xc[j] * xc[j];
  }
  #pragma unroll
  for (int m = 1; m < 64; m <<= 1) { s += __shfl_xor(s, m); ss += __shfl_xor(ss, m); }
  float mu = s * (1.f / 512.f);
  float rstd = rsqrtf(ss * (1.f / 512.f) - mu * mu + 1e-5f);
  ushort o[8];
  #pragma unroll
  for (int j = 0; j < 8; ++j) {
    int e = lane * 8 + j;
    o[j] = f2bf((xc[j] - mu) * rstd * scale[e] + bias[e]);
  }
  *(s16x8*)(outb + row * 512 + lane * 8) = *(s16x8*)o;
}

extern "C" void kernel_launch(void* const* d_in, const int* in_sizes, int n_in,
                              void* d_out, int out_size, void* d_ws, size_t ws_size,
                              hipStream_t stream)
{
  (void)in_sizes; (void)n_in; (void)out_size; (void)ws_size;
  const int T = 4096, E = 512, HD = 2048;
  const float* body = (const float*)d_in[0];
  const float* limb = (const float*)d_in[1];
  const float* qw = (const float*)d_in[2];  const float* qb = (const float*)d_in[3];
  const float* kw = (const float*)d_in[4];  const float* kb = (const float*)d_in[5];
  const float* vw = (const float*)d_in[6];  const float* vb = (const float*)d_in[7];
  const float* ow = (const float*)d_in[8];  const float* ob = (const float*)d_in[9];
  const float* w1 = (const float*)d_in[10]; const float* fb1 = (const float*)d_in[11];
  const float* w2 = (const float*)d_in[12]; const float* fb2 = (const float*)d_in[13];
  const float* nsc = (const float*)d_in[14]; const float* nbi = (const float*)d_in[15];
  const float* gw = (const float*)d_in[16];  const float* gb = (const float*)d_in[17];
  const void* temp = d_in[18];

  char* ws = (char*)d_ws;
  size_t off = 0;
  auto alloc = [&](size_t b) { char* p = ws + off; off += (b + 255) & ~(size_t)255; return p; };
  ushort* FW    = (ushort*)alloc((size_t)4 * 1536 * 512 * 2);
  ushort* WOT   = (ushort*)alloc((size_t)4 * E * E * 2);
  ushort* W1T   = (ushort*)alloc((size_t)2 * E * HD * 2);
  ushort* W2T   = (ushort*)alloc((size_t)2 * HD * E * 2);
  ushort* XB    = (ushort*)alloc((size_t)T * E * 2);
  ushort* XL    = (ushort*)alloc((size_t)T * E * 2);
  float*  PROJA = (float*)alloc((size_t)T * E * 4);
  float*  PROJB = (float*)alloc((size_t)T * E * 4);
  ushort* BODYb = (ushort*)alloc((size_t)T * E * 2);
  ushort* LIMBb = (ushort*)alloc((size_t)T * E * 2);
  ushort* BCRb  = (ushort*)alloc((size_t)T * E * 2);
  ushort* LCRb  = (ushort*)alloc((size_t)T * E * 2);
  ushort* GBb   = (ushort*)alloc((size_t)T * E * 2);
  ushort* GLb   = (ushort*)alloc((size_t)T * E * 2);
  ushort* QA    = (ushort*)alloc((size_t)T * E * 2);
  ushort* KA    = (ushort*)alloc((size_t)T * E * 2);
  ushort* VTA   = (ushort*)alloc((size_t)T * E * 2);
  ushort* QB    = (ushort*)alloc((size_t)T * E * 2);
  ushort* KB    = (ushort*)alloc((size_t)T * E * 2);
  ushort* VTB   = (ushort*)alloc((size_t)T * E * 2);
  ushort* AOA   = (ushort*)alloc((size_t)T * E * 2);
  ushort* AOB   = (ushort*)alloc((size_t)T * E * 2);
  ushort* H1A   = QA;     // 16 MB spans QA,KA,VTA,QB (dead by FFN)
  ushort* H1B   = KB;     // 16 MB spans KB,VTB,AOA,AOB (dead by FFN)
  float*  FFNA  = PROJA;  // reuse
  float*  FFNB  = PROJB;  // reuse

  transpose_all<<<8192, dim3(32, 8), 0, stream>>>(qw, kw, vw, ow, w1, w2, FW, WOT, W1T, W2T);
  cvt2_bf16<<<dim3(T * E / 1024, 2), 256, 0, stream>>>(body, limb, XB, XL);

  auto qkv_pair = [&](const ushort* A0, int t0, ushort* q0, ushort* k0, ushort* v0,
                      const ushort* A1, int t1, ushort* q1, ushort* k1, ushort* v1) {
    GemmArgs a{}, b{};
    int kv0 = t0 ^ (t0 >> 1), kv1 = t1 ^ (t1 >> 1);
    a.A = A0; a.Bt = FW + (size_t)t0 * 1536 * 512;
    a.b0 = qb + t0 * E; a.b1 = kb + kv0 * E; a.b2 = vb + kv0 * E;
    a.qo = q0; a.ko = k0; a.vto = v0; a.sp = temp; a.M = T; a.N = 1536; a.K = E; a.kind = 3;
    b = a;
    b.A = A1; b.Bt = FW + (size_t)t1 * 1536 * 512;
    b.b0 = qb + t1 * E; b.b1 = kb + kv1 * E; b.b2 = vb + kv1 * E;
    b.qo = q1; b.ko = k1; b.vto = v1;
    gemm_k<4, 4><<<dim3(12, 32, 2), 256, 0, stream>>>(a, b);
  };
  auto oproj_pair = [&](const ushort* A0, int i0, float* of0, ushort* ob0,
                        const ushort* A1, int i1, float* of1, ushort* ob1, int kind) {
    GemmArgs a{}, b{};
    a.A = A0; a.Bt = WOT + (size_t)i0 * E * E; a.b0 = ob + i0 * E;
    a.outf = of0; a.outb = ob0; a.M = T; a.N = E; a.K = E; a.kind = kind;
    b = a;
    b.A = A1; b.Bt = WOT + (size_t)i1 * E * E; b.b0 = ob + i1 * E;
    b.outf = of1; b.outb = ob1;
    gemm_k<2, 4><<<dim3(4, 64, 2), 256, 0, stream>>>(a, b);
  };

  // ---- self attention (both streams batched)
  qkv_pair(XB, 0, QA, KA, VTA, XL, 1, QB, KB, VTB);
  attn_core<<<dim3(512, 2), 256, 0, stream>>>(QA, KA, VTA, AOA, QB, KB, VTB, AOB);
  oproj_pair(AOA, 0, PROJA, nullptr, AOB, 1, PROJB, nullptr, 0);
  add_ln_ff2<<<dim3(T / 4, 2), 256, 0, stream>>>(body, PROJA, BODYb, limb, PROJB, LIMBb,
                                                 nsc, nbi, 0, 3);
  // ---- cross attention
  qkv_pair(BODYb, 2, QA, KA, VTA, LIMBb, 3, QB, KB, VTB);
  attn_core<<<dim3(512, 2), 256, 0, stream>>>(QA, KB, VTB, AOA, QB, KA, VTA, AOB);
  oproj_pair(AOA, 2, nullptr, BCRb, AOB, 3, nullptr, LCRb, 1);

  // ---- gated merge + LN (norm index 1 for BOTH, faithful to reference)
  gate_ln2<<<dim3(T / 4, 2), 256, 0, stream>>>(BODYb, BCRb, GBb, LIMBb, LCRb, GLb,
                                               gw, gb, nsc + E, nbi + E);

  // ---- FFN + residual LN -> final outputs
  {
    GemmArgs a{}, b{};
    a.A = GBb; a.Bt = W1T; a.b0 = fb1; a.outb = H1A;
    a.M = T; a.N = HD; a.K = E; a.kind = 2;
    b = a; b.A = GLb; b.Bt = W1T + (size_t)HD * E; b.b0 = fb1 + HD; b.outb = H1B;
    gemm_k<4, 4><<<dim3(16, 32, 2), 256, 0, stream>>>(a, b);
  }
  {
    GemmArgs a{}, b{};
    a.A = H1A; a.Bt = W2T; a.b0 = fb2; a.outf = FFNA;
    a.M = T; a.N = E; a.K = HD; a.kind = 0;
    b = a; b.A = H1B; b.Bt = W2T + (size_t)HD * E; b.b0 = fb2 + E; b.outf = FFNB;
    gemm_k<2, 4><<<dim3(4, 64, 2), 256, 0, stream>>>(a, b);
  }
  add_ln_bf2<<<dim3(T / 4, 2), 256, 0, stream>>>(GBb, FFNA, (float*)d_out,
                                                 GLb, FFNB, (float*)d_out + (size_t)T * E,
                                                 nsc, nbi, 2, 5);
}

// Round 7
// 377.430 us; speedup vs baseline: 1.8326x; 1.0705x over previous
//
#include <hip/hip_runtime.h>

#define AS1 __attribute__((address_space(1)))
#define AS3 __attribute__((address_space(3)))

typedef __attribute__((ext_vector_type(4))) float f32x4;
typedef __attribute__((ext_vector_type(8))) short s16x8;

static __device__ __forceinline__ ushort f2bf(float f) {
  union { float f; unsigned u; } x; x.f = f;
  unsigned r = x.u + 0x7FFFu + ((x.u >> 16) & 1u);
  return (ushort)(r >> 16);
}
static __device__ __forceinline__ float bf2f(ushort u) {
  union { unsigned u; float f; } x; x.u = ((unsigned)u) << 16; return x.f;
}
static __device__ __forceinline__ float ex2(float x) {
  return __builtin_amdgcn_exp2f(x);
}
static __device__ __forceinline__ unsigned cvt_pk_bf16(float a, float b) {
  unsigned r;
  asm("v_cvt_pk_bf16_f32 %0, %1, %2" : "=v"(r) : "v"(a), "v"(b));
  return r;
}
// tanh-form GELU via exp2: gelu(x) = x * (1 - 1/(e+1)), e = exp2(2*log2e*u)
static __device__ __forceinline__ float gelu_fast(float v) {
  float u = 0.7978845608028654f * (v + 0.044715f * v * v * v);
  float e = ex2(u * 2.885390081777927f);
  float r = __builtin_amdgcn_rcpf(e + 1.0f);
  return v - v * r;
}
static __device__ __forceinline__ float parse_scalar(const void* p) {
  int i = *(const int*)p;
  if (i > 0 && i < 1000000) return (float)i;
  union { int i; float f; } u; u.i = i; return u.f;
}

// ---------------- uber prep kernel: weight transpose+cvt, and input f32->bf16 cvt
// id<3072: fused QKV (FW[trip][1536][512]); 3072..4095: WOT; 4096..6143: W1T;
// 6144..8191: W2T; 8192..12287: cvt body/limb -> XB/XL
__global__ __launch_bounds__(256)
void transpose_all(const float* __restrict__ qw, const float* __restrict__ kw,
                   const float* __restrict__ vw, const float* __restrict__ ow,
                   const float* __restrict__ w1, const float* __restrict__ w2,
                   const float* __restrict__ body, const float* __restrict__ limb,
                   ushort* __restrict__ FW, ushort* __restrict__ WOT,
                   ushort* __restrict__ W1T, ushort* __restrict__ W2T,
                   ushort* __restrict__ XB, ushort* __restrict__ XL)
{
  __shared__ float tile[32][33];
  int id = blockIdx.x;
  if (id >= 8192) {
    int id2 = id - 8192;
    const float* in = (id2 >= 2048) ? limb : body;
    ushort* out = (id2 >= 2048) ? XL : XB;
    int j = id2 & 2047;
    int t = threadIdx.y * 32 + threadIdx.x;
    int i = (j * 256 + t) * 4;
    float4 v = *(const float4*)(in + i);
    ushort4 o;
    o.x = f2bf(v.x); o.y = f2bf(v.y); o.z = f2bf(v.z); o.w = f2bf(v.w);
    *(ushort4*)(out + i) = o;
    return;
  }
  const float* in; ushort* out; int K, N, tx, ty;
  if (id < 3072) {
    int trip = id / 768, r = id - trip * 768, which = r >> 8, t2 = r & 255;
    int widx = (which == 0) ? trip : (trip ^ (trip >> 1));
    in = ((which == 0) ? qw : (which == 1) ? kw : vw) + (size_t)widx * 512 * 512;
    out = FW + (size_t)trip * 1536 * 512 + (size_t)which * 512 * 512;
    K = 512; N = 512; tx = t2 & 15; ty = t2 >> 4;
  } else if (id < 4096) {
    int r = id - 3072, wi = r >> 8, t2 = r & 255;
    in = ow + (size_t)wi * 512 * 512; out = WOT + (size_t)wi * 512 * 512;
    K = 512; N = 512; tx = t2 & 15; ty = t2 >> 4;
  } else if (id < 6144) {
    int r = id - 4096, s = r >> 10, t2 = r & 1023;
    in = w1 + (size_t)s * 512 * 2048; out = W1T + (size_t)s * 2048 * 512;
    K = 512; N = 2048; tx = t2 & 63; ty = t2 >> 6;
  } else {
    int r = id - 6144, s = r >> 10, t2 = r & 1023;
    in = w2 + (size_t)s * 2048 * 512; out = W2T + (size_t)s * 512 * 2048;
    K = 2048; N = 512; tx = t2 & 15; ty = t2 >> 4;
  }
  int nb = tx * 32, kb = ty * 32;
  int x = threadIdx.x, y = threadIdx.y;
  #pragma unroll
  for (int i = 0; i < 4; ++i)
    tile[y + i * 8][x] = in[(size_t)(kb + y + i * 8) * N + nb + x];
  __syncthreads();
  #pragma unroll
  for (int i = 0; i < 4; ++i)
    out[(size_t)(nb + y + i * 8) * K + kb + x] = f2bf(tile[x][y + i * 8]);
}

// ---------------- GEMM: C[M][N] = A[M][K](bf16) @ Bt[N][K](bf16) + bias
// kind: 0 f32 out, 1 bf16 out, 2 bf16+fastGELU out, 3 QKV split
struct GemmArgs {
  const ushort* A; const ushort* Bt;
  const float *b0, *b1, *b2;
  float* outf; ushort* outb;
  ushort *qo, *ko, *vto;
  const void* sp;
  int M, N, K, kind;
};

template<int FM, int FN>
__global__ __launch_bounds__(256)
void gemm_k(GemmArgs g0, GemmArgs g1)
{
  constexpr int BM = FM * 32, BN = FN * 32;
  __shared__ ushort As[2][BM * 64];
  __shared__ ushort Bs[2][BN * 64];
  GemmArgs g = blockIdx.z ? g1 : g0;
  const int t = threadIdx.x, lane = t & 63, w = t >> 6;
  const int lr = lane & 15, gq = lane >> 4;
  const int wr = w >> 1, wc = w & 1;
  const int m0 = blockIdx.y * BM, n0 = blockIdx.x * BN;
  const int K = g.K;
  const int nk = K >> 6;

  auto stage = [&](int kt, int buf) {
    #pragma unroll
    for (int p = 0; p < FM; ++p) {
      int c = p * 256 + t, row = c >> 3, sl = c & 7;
      const ushort* src = g.A + (size_t)(m0 + row) * K + kt * 64 + ((sl ^ (row & 7)) << 3);
      __builtin_amdgcn_global_load_lds((const AS1 void*)src,
          (AS3 void*)(As[buf] + (size_t)(p * 256 + (t & ~63)) * 8), 16, 0, 0);
    }
    #pragma unroll
    for (int p = 0; p < FN; ++p) {
      int c = p * 256 + t, row = c >> 3, sl = c & 7;
      const ushort* src = g.Bt + (size_t)(n0 + row) * K + kt * 64 + ((sl ^ (row & 7)) << 3);
      __builtin_amdgcn_global_load_lds((const AS1 void*)src,
          (AS3 void*)(Bs[buf] + (size_t)(p * 256 + (t & ~63)) * 8), 16, 0, 0);
    }
  };

  f32x4 acc[FM][FN];
  f32x4 zero = {0.f, 0.f, 0.f, 0.f};
  #pragma unroll
  for (int m = 0; m < FM; ++m)
    #pragma unroll
    for (int n = 0; n < FN; ++n) acc[m][n] = zero;

  stage(0, 0);
  __syncthreads();
  for (int kt = 0; kt < nk; ++kt) {
    int cur = kt & 1;
    const ushort* Ab = As[cur];
    const ushort* Bb = Bs[cur];
    if (kt + 1 < nk) stage(kt + 1, cur ^ 1);
    #pragma unroll
    for (int ks = 0; ks < 2; ++ks) {
      s16x8 af[FM], bfv[FN];
      #pragma unroll
      for (int m = 0; m < FM; ++m) {
        int row = wr * (FM * 16) + m * 16 + lr;
        af[m] = *(const s16x8*)(Ab + row * 64 + (((ks * 4 + gq) ^ (row & 7)) << 3));
      }
      #pragma unroll
      for (int n = 0; n < FN; ++n) {
        int row = wc * (FN * 16) + n * 16 + lr;
        bfv[n] = *(const s16x8*)(Bb + row * 64 + (((ks * 4 + gq) ^ (row & 7)) << 3));
      }
      __builtin_amdgcn_s_setprio(1);
      #pragma unroll
      for (int m = 0; m < FM; ++m)
        #pragma unroll
        for (int n = 0; n < FN; ++n)
          acc[m][n] = __builtin_amdgcn_mfma_f32_16x16x32_bf16(af[m], bfv[n], acc[m][n], 0, 0, 0);
      __builtin_amdgcn_s_setprio(0);
    }
    __syncthreads();
  }

  float qs = 1.0f;
  if (g.kind == 3 && g.sp) qs = 0.125f / parse_scalar(g.sp) * 1.4426950408889634f;
  #pragma unroll
  for (int n = 0; n < FN; ++n) {
    int col = n0 + wc * (FN * 16) + n * 16 + lr;
    int seg = col >> 9, cm = col & 511;
    float bv;
    if (g.kind == 3) bv = (seg == 0) ? g.b0[cm] : (seg == 1) ? g.b1[cm] : g.b2[cm];
    else bv = g.b0 ? g.b0[col] : 0.f;
    #pragma unroll
    for (int m = 0; m < FM; ++m) {
      int rowb = m0 + wr * (FM * 16) + m * 16 + 4 * gq;
      if (g.kind == 3) {
        if (seg == 2) {
          int d = cm & 63, hh = cm >> 6, bb = rowb >> 10, s = rowb & 1023;
          ushort4 pk;
          pk.x = f2bf(acc[m][n][0] + bv); pk.y = f2bf(acc[m][n][1] + bv);
          pk.z = f2bf(acc[m][n][2] + bv); pk.w = f2bf(acc[m][n][3] + bv);
          *(ushort4*)(g.vto + (((size_t)(bb * 8 + hh) * 64 + d) << 10) + s) = pk;
        } else if (seg == 1) {
          #pragma unroll
          for (int r = 0; r < 4; ++r)
            g.ko[(size_t)(rowb + r) * 512 + cm] = f2bf(acc[m][n][r] + bv);
        } else {
          #pragma unroll
          for (int r = 0; r < 4; ++r)
            g.qo[(size_t)(rowb + r) * 512 + cm] = f2bf((acc[m][n][r] + bv) * qs);
        }
      } else {
        #pragma unroll
        for (int r = 0; r < 4; ++r) {
          float v = acc[m][n][r] + bv;
          if (g.kind == 2) v = gelu_fast(v);
          if (g.kind == 0) g.outf[(size_t)(rowb + r) * g.N + col] = v;
          else g.outb[(size_t)(rowb + r) * g.N + col] = f2bf(v);
        }
      }
    }
  }
}

// ---------------- flash attention core v3 (unchanged from R5, passing)
__global__ __launch_bounds__(256)
void attn_core(const ushort* __restrict__ Q0, const ushort* __restrict__ K0,
               const ushort* __restrict__ V0, ushort* __restrict__ O0,
               const ushort* __restrict__ Q1, const ushort* __restrict__ K1,
               const ushort* __restrict__ V1, ushort* __restrict__ O1)
{
  __shared__ ushort Ks[2][64 * 64];
  __shared__ ushort Vs[2][64 * 64];
  __shared__ ushort Ps[4][1024];
  const int str = blockIdx.y;
  const ushort* Q = str ? Q1 : Q0;
  const ushort* Kx = str ? K1 : K0;
  const ushort* VT = str ? V1 : V0;
  ushort* O = str ? O1 : O0;

  const int t = threadIdx.x, lane = t & 63, w = t >> 6;
  const int lr = lane & 15, g = lane >> 4;
  int bid = blockIdx.x;
  int L = (bid & 7) * 64 + (bid >> 3);
  int bh = L >> 4, qt = L & 15;
  size_t tbase = ((size_t)(bh >> 3) << 19) + ((size_t)(bh & 7) << 6);
  const ushort* Kbase = Kx + tbase;
  const ushort* Vbase = VT + ((size_t)bh << 16);
  int q0 = qt * 64 + w * 16;
  char* myPs = (char*)Ps[w];
  const int psw = (lr & 7) << 4;

  auto stage = [&](int kt, int buf) {
    #pragma unroll
    for (int p = 0; p < 2; ++p) {
      int c = p * 256 + t, row = c >> 3, sl = c & 7;
      const ushort* src = Kbase + (size_t)(kt * 64 + row) * 512 + ((sl ^ (row & 7)) << 3);
      __builtin_amdgcn_global_load_lds((const AS1 void*)src,
          (AS3 void*)(Ks[buf] + (size_t)(p * 256 + (t & ~63)) * 8), 16, 0, 0);
    }
    #pragma unroll
    for (int p = 0; p < 2; ++p) {
      int c = p * 256 + t, row = c >> 3, sl = c & 7;
      const ushort* src = Vbase + (size_t)row * 1024 + kt * 64 + ((sl ^ (row & 7)) << 3);
      __builtin_amdgcn_global_load_lds((const AS1 void*)src,
          (AS3 void*)(Vs[buf] + (size_t)(p * 256 + (t & ~63)) * 8), 16, 0, 0);
    }
  };

  s16x8 qf[2];
  #pragma unroll
  for (int ks = 0; ks < 2; ++ks)
    qf[ks] = *(const s16x8*)(Q + tbase + (size_t)(q0 + lr) * 512 + ks * 32 + g * 8);

  f32x4 po[4];
  f32x4 zero = {0.f, 0.f, 0.f, 0.f};
  #pragma unroll
  for (int dt = 0; dt < 4; ++dt) po[dt] = zero;
  float mrow = -1e30f, lsum = 0.f;

  stage(0, 0);
  __syncthreads();
  #pragma unroll 2
  for (int kt = 0; kt < 16; ++kt) {
    int cur = kt & 1;
    const ushort* Kb = Ks[cur];
    const ushort* Vb = Vs[cur];
    if (kt < 15) stage(kt + 1, cur ^ 1);

    f32x4 sc[4];
    #pragma unroll
    for (int c = 0; c < 4; ++c) {
      sc[c] = zero;
      #pragma unroll
      for (int ks = 0; ks < 2; ++ks) {
        int row = c * 16 + lr;
        s16x8 kf = *(const s16x8*)(Kb + row * 64 + (((ks * 4 + g) ^ (row & 7)) << 3));
        sc[c] = __builtin_amdgcn_mfma_f32_16x16x32_bf16(kf, qf[ks], sc[c], 0, 0, 0);
      }
    }

    float tm = sc[0][0];
    #pragma unroll
    for (int c = 0; c < 4; ++c)
      #pragma unroll
      for (int r = 0; r < 4; ++r) tm = fmaxf(tm, sc[c][r]);
    tm = fmaxf(tm, __shfl_xor(tm, 16));
    tm = fmaxf(tm, __shfl_xor(tm, 32));
    float nm = fmaxf(mrow, tm);
    float fr = ex2(mrow - nm);
    float ts = 0.f;
    #pragma unroll
    for (int c = 0; c < 4; ++c)
      #pragma unroll
      for (int r = 0; r < 4; ++r) {
        float pv = ex2(sc[c][r] - nm);
        sc[c][r] = pv;
        ts += pv;
      }
    ts += __shfl_xor(ts, 16);
    ts += __shfl_xor(ts, 32);
    lsum = lsum * fr + ts;
    mrow = nm;
    #pragma unroll
    for (int dt = 0; dt < 4; ++dt) po[dt] *= fr;

    #pragma unroll
    for (int c = 0; c < 4; ++c) {
      uint2 d;
      d.x = cvt_pk_bf16(sc[c][0], sc[c][1]);
      d.y = cvt_pk_bf16(sc[c][2], sc[c][3]);
      *(uint2*)(myPs + lr * 128 + ((c * 32 + g * 8) ^ psw)) = d;
    }
    s16x8 paf[2];
    #pragma unroll
    for (int ks = 0; ks < 2; ++ks)
      paf[ks] = *(const s16x8*)(myPs + lr * 128 + ((ks * 64 + g * 16) ^ psw));

    __builtin_amdgcn_s_setprio(1);
    #pragma unroll
    for (int dt = 0; dt < 4; ++dt) {
      int vrow = dt * 16 + lr;
      #pragma unroll
      for (int ks = 0; ks < 2; ++ks) {
        s16x8 vf = *(const s16x8*)(Vb + vrow * 64 + (((ks * 4 + g) ^ (vrow & 7)) << 3));
        po[dt] = __builtin_amdgcn_mfma_f32_16x16x32_bf16(vf, paf[ks], po[dt], 0, 0, 0);
      }
    }
    __builtin_amdgcn_s_setprio(0);
    __syncthreads();
  }

  float inv = 1.0f / lsum;
  #pragma unroll
  for (int dt = 0; dt < 4; ++dt) {
    ushort4 pk;
    pk.x = f2bf(po[dt][0] * inv);
    pk.y = f2bf(po[dt][1] * inv);
    pk.z = f2bf(po[dt][2] * inv);
    pk.w = f2bf(po[dt][3] * inv);
    *(ushort4*)(O + tbase + (size_t)(q0 + lr) * 512 + dt * 16 + 4 * g) = pk;
  }
}

// ---------------- LN(a_f32 + b_bf16) -> bf16, batched pair
__global__ __launch_bounds__(256)
void add_ln_fb2(const float* __restrict__ a0, const ushort* __restrict__ b0,
                ushort* __restrict__ o0, const float* __restrict__ a1,
                const ushort* __restrict__ b1, ushort* __restrict__ o1,
                const float* __restrict__ nsc, const float* __restrict__ nbi,
                int i0, int i1)
{
  const float* a = blockIdx.y ? a1 : a0;
  const ushort* b = blockIdx.y ? b1 : b0;
  ushort* outb = blockIdx.y ? o1 : o0;
  const float* scale = nsc + (blockIdx.y ? i1 : i0) * 512;
  const float* bias = nbi + (blockIdx.y ? i1 : i0) * 512;
  const int lane = threadIdx.x & 63, w = threadIdx.x >> 6;
  const size_t row = blockIdx.x * 4 + w;
  s16x8 bv8 = *(const s16x8*)(b + row * 512 + lane * 8);
  float x[8];
  #pragma unroll
  for (int j = 0; j < 8; j += 4) {
    float4 av = *(const float4*)(a + row * 512 + lane * 8 + j);
    x[j] = av.x + bf2f((ushort)bv8[j]);
    x[j + 1] = av.y + bf2f((ushort)bv8[j + 1]);
    x[j + 2] = av.z + bf2f((ushort)bv8[j + 2]);
    x[j + 3] = av.w + bf2f((ushort)bv8[j + 3]);
  }
  float s = 0.f, ss = 0.f;
  #pragma unroll
  for (int j = 0; j < 8; ++j) { s += x[j]; ss += x[j] * x[j]; }
  #pragma unroll
  for (int m = 1; m < 64; m <<= 1) { s += __shfl_xor(s, m); ss += __shfl_xor(ss, m); }
  float mu = s * (1.f / 512.f);
  float rstd = rsqrtf(ss * (1.f / 512.f) - mu * mu + 1e-5f);
  ushort o[8];
  #pragma unroll
  for (int j = 0; j < 8; ++j) {
    int e = lane * 8 + j;
    o[j] = f2bf((x[j] - mu) * rstd * scale[e] + bias[e]);
  }
  *(s16x8*)(outb + row * 512 + lane * 8) = *(s16x8*)o;
}

// ---------------- LN(a_bf16 + b_bf16) -> f32 final, batched pair
__global__ __launch_bounds__(256)
void add_ln_bb2(const ushort* __restrict__ a0, const ushort* __restrict__ b0,
                float* __restrict__ o0, const ushort* __restrict__ a1,
                const ushort* __restrict__ b1, float* __restrict__ o1,
                const float* __restrict__ nsc, const float* __restrict__ nbi,
                int i0, int i1)
{
  const ushort* a = blockIdx.y ? a1 : a0;
  const ushort* b = blockIdx.y ? b1 : b0;
  float* outf = blockIdx.y ? o1 : o0;
  const float* scale = nsc + (blockIdx.y ? i1 : i0) * 512;
  const float* bias = nbi + (blockIdx.y ? i1 : i0) * 512;
  const int lane = threadIdx.x & 63, w = threadIdx.x >> 6;
  const size_t row = blockIdx.x * 4 + w;
  s16x8 av = *(const s16x8*)(a + row * 512 + lane * 8);
  s16x8 bv = *(const s16x8*)(b + row * 512 + lane * 8);
  float x[8];
  #pragma unroll
  for (int j = 0; j < 8; ++j)
    x[j] = bf2f((ushort)av[j]) + bf2f((ushort)bv[j]);
  float s = 0.f, ss = 0.f;
  #pragma unroll
  for (int j = 0; j < 8; ++j) { s += x[j]; ss += x[j] * x[j]; }
  #pragma unroll
  for (int m = 1; m < 64; m <<= 1) { s += __shfl_xor(s, m); ss += __shfl_xor(ss, m); }
  float mu = s * (1.f / 512.f);
  float rstd = rsqrtf(ss * (1.f / 512.f) - mu * mu + 1e-5f);
  float o[8];
  #pragma unroll
  for (int j = 0; j < 8; ++j) {
    int e = lane * 8 + j;
    o[j] = (x[j] - mu) * rstd * scale[e] + bias[e];
  }
  *(float4*)(outf + row * 512 + lane * 8) = *(float4*)o;
  *(float4*)(outf + row * 512 + lane * 8 + 4) = *(float4*)(o + 4);
}

// ---------------- gated merge + LN, bf16 in/out, batched pair
__global__ __launch_bounds__(256)
void gate_ln2(const ushort* __restrict__ x0, const ushort* __restrict__ c0,
              ushort* __restrict__ o0, const ushort* __restrict__ x1,
              const ushort* __restrict__ c1, ushort* __restrict__ o1,
              const float* __restrict__ gw, const float* __restrict__ gb,
              const float* __restrict__ scale, const float* __restrict__ bias)
{
  const ushort* x = blockIdx.y ? x1 : x0;
  const ushort* cr = blockIdx.y ? c1 : c0;
  ushort* outb = blockIdx.y ? o1 : o0;
  const int lane = threadIdx.x & 63, w = threadIdx.x >> 6;
  const size_t row = blockIdx.x * 4 + w;
  s16x8 xv8 = *(const s16x8*)(x + row * 512 + lane * 8);
  s16x8 cv8 = *(const s16x8*)(cr + row * 512 + lane * 8);
  float xv[8], cv[8];
  #pragma unroll
  for (int j = 0; j < 8; ++j) { xv[j] = bf2f((ushort)xv8[j]); cv[j] = bf2f((ushort)cv8[j]); }
  float d0 = 0.f, d1 = 0.f;
  #pragma unroll
  for (int j = 0; j < 8; ++j) {
    int e = lane * 8 + j;
    float2 g0 = *(const float2*)(gw + 2 * e);
    float2 g1 = *(const float2*)(gw + 2 * (512 + e));
    d0 += xv[j] * g0.x + cv[j] * g1.x;
    d1 += xv[j] * g0.y + cv[j] * g1.y;
  }
  #pragma unroll
  for (int m = 1; m < 64; m <<= 1) { d0 += __shfl_xor(d0, m); d1 += __shfl_xor(d1, m); }
  d0 += gb[0]; d1 += gb[1];
  float mx = fmaxf(d0, d1);
  float e0 = __expf(d0 - mx), e1 = __expf(d1 - mx);
  float inv = 1.0f / (e0 + e1);
  float g0w = e0 * inv, g1w = e1 * inv;
  float xc[8];
  float s = 0.f, ss = 0.f;
  #pragma unroll
  for (int j = 0; j < 8; ++j) {
    xc[j] = xv[j] * g0w + cv[j] * g1w;
    s += xc[j]; ss += xc[j] * xc[j];
  }
  #pragma unroll
  for (int m = 1; m < 64; m <<= 1) { s += __shfl_xor(s, m); ss += __shfl_xor(ss, m); }
  float mu = s * (1.f / 512.f);
  float rstd = rsqrtf(ss * (1.f / 512.f) - mu * mu + 1e-5f);
  ushort o[8];
  #pragma unroll
  for (int j = 0; j < 8; ++j) {
    int e = lane * 8 + j;
    o[j] = f2bf((xc[j] - mu) * rstd * scale[e] + bias[e]);
  }
  *(s16x8*)(outb + row * 512 + lane * 8) = *(s16x8*)o;
}

extern "C" void kernel_launch(void* const* d_in, const int* in_sizes, int n_in,
                              void* d_out, int out_size, void* d_ws, size_t ws_size,
                              hipStream_t stream)
{
  (void)in_sizes; (void)n_in; (void)out_size; (void)ws_size;
  const int T = 4096, E = 512, HD = 2048;
  const float* body = (const float*)d_in[0];
  const float* limb = (const float*)d_in[1];
  const float* qw = (const float*)d_in[2];  const float* qb = (const float*)d_in[3];
  const float* kw = (const float*)d_in[4];  const float* kb = (const float*)d_in[5];
  const float* vw = (const float*)d_in[6];  const float* vb = (const float*)d_in[7];
  const float* ow = (const float*)d_in[8];  const float* ob = (const float*)d_in[9];
  const float* w1 = (const float*)d_in[10]; const float* fb1 = (const float*)d_in[11];
  const float* w2 = (const float*)d_in[12]; const float* fb2 = (const float*)d_in[13];
  const float* nsc = (const float*)d_in[14]; const float* nbi = (const float*)d_in[15];
  const float* gw = (const float*)d_in[16];  const float* gb = (const float*)d_in[17];
  const void* temp = d_in[18];

  char* ws = (char*)d_ws;
  size_t off = 0;
  auto alloc = [&](size_t b) { char* p = ws + off; off += (b + 255) & ~(size_t)255; return p; };
  ushort* FW    = (ushort*)alloc((size_t)4 * 1536 * 512 * 2);
  ushort* WOT   = (ushort*)alloc((size_t)4 * E * E * 2);
  ushort* W1T   = (ushort*)alloc((size_t)2 * E * HD * 2);
  ushort* W2T   = (ushort*)alloc((size_t)2 * HD * E * 2);
  ushort* XB    = (ushort*)alloc((size_t)T * E * 2);
  ushort* XL    = (ushort*)alloc((size_t)T * E * 2);
  ushort* PROJA = (ushort*)alloc((size_t)T * E * 2);
  ushort* PROJB = (ushort*)alloc((size_t)T * E * 2);
  ushort* BODYb = (ushort*)alloc((size_t)T * E * 2);
  ushort* LIMBb = (ushort*)alloc((size_t)T * E * 2);
  ushort* BCRb  = (ushort*)alloc((size_t)T * E * 2);
  ushort* LCRb  = (ushort*)alloc((size_t)T * E * 2);
  ushort* GBb   = (ushort*)alloc((size_t)T * E * 2);
  ushort* GLb   = (ushort*)alloc((size_t)T * E * 2);
  ushort* QA    = (ushort*)alloc((size_t)T * E * 2);
  ushort* KA    = (ushort*)alloc((size_t)T * E * 2);
  ushort* VTA   = (ushort*)alloc((size_t)T * E * 2);
  ushort* QB    = (ushort*)alloc((size_t)T * E * 2);
  ushort* KB    = (ushort*)alloc((size_t)T * E * 2);
  ushort* VTB   = (ushort*)alloc((size_t)T * E * 2);
  ushort* AOA   = (ushort*)alloc((size_t)T * E * 2);
  ushort* AOB   = (ushort*)alloc((size_t)T * E * 2);
  ushort* H1A   = QA;     // 16 MB spans QA,KA,VTA,QB (dead by FFN)
  ushort* H1B   = KB;     // 16 MB spans KB,VTB,AOA,AOB (dead by FFN)
  ushort* F2A   = PROJA;  // FFN2 bf16 out, reuse (dead after add_ln_fb2)
  ushort* F2B   = PROJB;

  transpose_all<<<12288, dim3(32, 8), 0, stream>>>(qw, kw, vw, ow, w1, w2, body, limb,
                                                   FW, WOT, W1T, W2T, XB, XL);

  auto qkv_pair = [&](const ushort* A0, int t0, ushort* q0, ushort* k0, ushort* v0,
                      const ushort* A1, int t1, ushort* q1, ushort* k1, ushort* v1) {
    GemmArgs a{}, b{};
    int kv0 = t0 ^ (t0 >> 1), kv1 = t1 ^ (t1 >> 1);
    a.A = A0; a.Bt = FW + (size_t)t0 * 1536 * 512;
    a.b0 = qb + t0 * E; a.b1 = kb + kv0 * E; a.b2 = vb + kv0 * E;
    a.qo = q0; a.ko = k0; a.vto = v0; a.sp = temp; a.M = T; a.N = 1536; a.K = E; a.kind = 3;
    b = a;
    b.A = A1; b.Bt = FW + (size_t)t1 * 1536 * 512;
    b.b0 = qb + t1 * E; b.b1 = kb + kv1 * E; b.b2 = vb + kv1 * E;
    b.qo = q1; b.ko = k1; b.vto = v1;
    gemm_k<4, 4><<<dim3(12, 32, 2), 256, 0, stream>>>(a, b);
  };
  auto oproj_pair = [&](const ushort* A0, int i0, ushort* ob0,
                        const ushort* A1, int i1, ushort* ob1) {
    GemmArgs a{}, b{};
    a.A = A0; a.Bt = WOT + (size_t)i0 * E * E; a.b0 = ob + i0 * E;
    a.outb = ob0; a.M = T; a.N = E; a.K = E; a.kind = 1;
    b = a;
    b.A = A1; b.Bt = WOT + (size_t)i1 * E * E; b.b0 = ob + i1 * E;
    b.outb = ob1;
    gemm_k<2, 2><<<dim3(8, 64, 2), 256, 0, stream>>>(a, b);
  };

  // ---- self attention (both streams batched)
  qkv_pair(XB, 0, QA, KA, VTA, XL, 1, QB, KB, VTB);
  attn_core<<<dim3(512, 2), 256, 0, stream>>>(QA, KA, VTA, AOA, QB, KB, VTB, AOB);
  oproj_pair(AOA, 0, PROJA, AOB, 1, PROJB);
  add_ln_fb2<<<dim3(T / 4, 2), 256, 0, stream>>>(body, PROJA, BODYb, limb, PROJB, LIMBb,
                                                 nsc, nbi, 0, 3);
  // ---- cross attention
  qkv_pair(BODYb, 2, QA, KA, VTA, LIMBb, 3, QB, KB, VTB);
  attn_core<<<dim3(512, 2), 256, 0, stream>>>(QA, KB, VTB, AOA, QB, KA, VTA, AOB);
  oproj_pair(AOA, 2, BCRb, AOB, 3, LCRb);

  // ---- gated merge + LN (norm index 1 for BOTH, faithful to reference)
  gate_ln2<<<dim3(T / 4, 2), 256, 0, stream>>>(BODYb, BCRb, GBb, LIMBb, LCRb, GLb,
                                               gw, gb, nsc + E, nbi + E);

  // ---- FFN + residual LN -> final outputs
  {
    GemmArgs a{}, b{};
    a.A = GBb; a.Bt = W1T; a.b0 = fb1; a.outb = H1A;
    a.M = T; a.N = HD; a.K = E; a.kind = 2;
    b = a; b.A = GLb; b.Bt = W1T + (size_t)HD * E; b.b0 = fb1 + HD; b.outb = H1B;
    gemm_k<4, 4><<<dim3(16, 32, 2), 256, 0, stream>>>(a, b);
  }
  {
    GemmArgs a{}, b{};
    a.A = H1A; a.Bt = W2T; a.b0 = fb2; a.outb = F2A;
    a.M = T; a.N = E; a.K = HD; a.kind = 1;
    b = a; b.A = H1B; b.Bt = W2T + (size_t)HD * E; b.b0 = fb2 + E; b.outb = F2B;
    gemm_k<2, 2><<<dim3(8, 64, 2), 256, 0, stream>>>(a, b);
  }
  add_ln_bb2<<<dim3(T / 4, 2), 256, 0, stream>>>(GBb, F2A, (float*)d_out,
                                                 GLb, F2B, (float*)d_out + (size_t)T * E,
                                                 nsc, nbi, 2, 5);
}

// Round 9
// 369.282 us; speedup vs baseline: 1.8730x; 1.0221x over previous
//
#include <hip/hip_runtime.h>

#define AS1 __attribute__((address_space(1)))
#define AS3 __attribute__((address_space(3)))

typedef __attribute__((ext_vector_type(4))) float f32x4;
typedef __attribute__((ext_vector_type(8))) short s16x8;

static __device__ __forceinline__ ushort f2bf(float f) {
  union { float f; unsigned u; } x; x.f = f;
  unsigned r = x.u + 0x7FFFu + ((x.u >> 16) & 1u);
  return (ushort)(r >> 16);
}
static __device__ __forceinline__ float bf2f(ushort u) {
  union { unsigned u; float f; } x; x.u = ((unsigned)u) << 16; return x.f;
}
static __device__ __forceinline__ float ex2(float x) {
  return __builtin_amdgcn_exp2f(x);
}
static __device__ __forceinline__ unsigned cvt_pk_bf16(float a, float b) {
  unsigned r;
  asm("v_cvt_pk_bf16_f32 %0, %1, %2" : "=v"(r) : "v"(a), "v"(b));
  return r;
}
// tanh-form GELU via exp2: gelu(x) = x * (1 - 1/(e+1)), e = exp2(2*log2e*u)
static __device__ __forceinline__ float gelu_fast(float v) {
  float u = 0.7978845608028654f * (v + 0.044715f * v * v * v);
  float e = ex2(u * 2.885390081777927f);
  float r = __builtin_amdgcn_rcpf(e + 1.0f);
  return v - v * r;
}
static __device__ __forceinline__ float parse_scalar(const void* p) {
  int i = *(const int*)p;
  if (i > 0 && i < 1000000) return (float)i;
  union { int i; float f; } u; u.i = i; return u.f;
}

// ---------------- uber prep kernel (unchanged)
__global__ __launch_bounds__(256)
void transpose_all(const float* __restrict__ qw, const float* __restrict__ kw,
                   const float* __restrict__ vw, const float* __restrict__ ow,
                   const float* __restrict__ w1, const float* __restrict__ w2,
                   const float* __restrict__ body, const float* __restrict__ limb,
                   ushort* __restrict__ FW, ushort* __restrict__ WOT,
                   ushort* __restrict__ W1T, ushort* __restrict__ W2T,
                   ushort* __restrict__ XB, ushort* __restrict__ XL)
{
  __shared__ float tile[32][33];
  int id = blockIdx.x;
  if (id >= 8192) {
    int id2 = id - 8192;
    const float* in = (id2 >= 2048) ? limb : body;
    ushort* out = (id2 >= 2048) ? XL : XB;
    int j = id2 & 2047;
    int t = threadIdx.y * 32 + threadIdx.x;
    int i = (j * 256 + t) * 4;
    float4 v = *(const float4*)(in + i);
    ushort4 o;
    o.x = f2bf(v.x); o.y = f2bf(v.y); o.z = f2bf(v.z); o.w = f2bf(v.w);
    *(ushort4*)(out + i) = o;
    return;
  }
  const float* in; ushort* out; int K, N, tx, ty;
  if (id < 3072) {
    int trip = id / 768, r = id - trip * 768, which = r >> 8, t2 = r & 255;
    int widx = (which == 0) ? trip : (trip ^ (trip >> 1));
    in = ((which == 0) ? qw : (which == 1) ? kw : vw) + (size_t)widx * 512 * 512;
    out = FW + (size_t)trip * 1536 * 512 + (size_t)which * 512 * 512;
    K = 512; N = 512; tx = t2 & 15; ty = t2 >> 4;
  } else if (id < 4096) {
    int r = id - 3072, wi = r >> 8, t2 = r & 255;
    in = ow + (size_t)wi * 512 * 512; out = WOT + (size_t)wi * 512 * 512;
    K = 512; N = 512; tx = t2 & 15; ty = t2 >> 4;
  } else if (id < 6144) {
    int r = id - 4096, s = r >> 10, t2 = r & 1023;
    in = w1 + (size_t)s * 512 * 2048; out = W1T + (size_t)s * 2048 * 512;
    K = 512; N = 2048; tx = t2 & 63; ty = t2 >> 6;
  } else {
    int r = id - 6144, s = r >> 10, t2 = r & 1023;
    in = w2 + (size_t)s * 2048 * 512; out = W2T + (size_t)s * 512 * 2048;
    K = 2048; N = 512; tx = t2 & 15; ty = t2 >> 4;
  }
  int nb = tx * 32, kb = ty * 32;
  int x = threadIdx.x, y = threadIdx.y;
  #pragma unroll
  for (int i = 0; i < 4; ++i)
    tile[y + i * 8][x] = in[(size_t)(kb + y + i * 8) * N + nb + x];
  __syncthreads();
  #pragma unroll
  for (int i = 0; i < 4; ++i)
    out[(size_t)(nb + y + i * 8) * K + kb + x] = f2bf(tile[x][y + i * 8]);
}

// ---------------- GEMM: C[M][N] = A[M][K](bf16) @ Bt[N][K](bf16) + bias
// Single-buffered LDS (m97 structure: 2-barrier loop, implicit cross-block overlap),
// XCD-chunked tile swizzle. kind: 0 f32, 1 bf16, 2 bf16+fastGELU, 3 QKV split
struct GemmArgs {
  const ushort* A; const ushort* Bt;
  const float *b0, *b1, *b2;
  float* outf; ushort* outb;
  ushort *qo, *ko, *vto;
  const void* sp;
  int M, N, K, kind;
};

template<int FM, int FN>
__global__ __launch_bounds__(256)
void gemm_k(GemmArgs g0, GemmArgs g1)
{
  constexpr int BM = FM * 32, BN = FN * 32;
  __shared__ ushort As[BM * 64];  // single buffer: 32 KB for <4,4>, 24 KB for <2,4>
  __shared__ ushort Bs[BN * 64];
  // bijective XCD-chunk swizzle (all grids have nwg % 8 == 0)
  const int nx = gridDim.x, nxy = nx * gridDim.y;
  const int nwg = nxy * gridDim.z;
  int bid = blockIdx.x + nx * blockIdx.y + nxy * blockIdx.z;
  int sw = (nwg & 7) ? bid : ((bid & 7) * (nwg >> 3) + (bid >> 3));
  const int bz = sw / nxy;
  int r2 = sw - bz * nxy;
  const int by = r2 / nx, bx = r2 - by * nx;
  GemmArgs g = bz ? g1 : g0;
  const int t = threadIdx.x, lane = t & 63, w = t >> 6;
  const int lr = lane & 15, gq = lane >> 4;
  const int wr = w >> 1, wc = w & 1;
  const int m0 = by * BM, n0 = bx * BN;
  const int K = g.K;
  const int nk = K >> 6;

  auto stage = [&](int kt) {
    #pragma unroll
    for (int p = 0; p < FM; ++p) {
      int c = p * 256 + t, row = c >> 3, sl = c & 7;
      const ushort* src = g.A + (size_t)(m0 + row) * K + kt * 64 + ((sl ^ (row & 7)) << 3);
      __builtin_amdgcn_global_load_lds((const AS1 void*)src,
          (AS3 void*)(As + (size_t)(p * 256 + (t & ~63)) * 8), 16, 0, 0);
    }
    #pragma unroll
    for (int p = 0; p < FN; ++p) {
      int c = p * 256 + t, row = c >> 3, sl = c & 7;
      const ushort* src = g.Bt + (size_t)(n0 + row) * K + kt * 64 + ((sl ^ (row & 7)) << 3);
      __builtin_amdgcn_global_load_lds((const AS1 void*)src,
          (AS3 void*)(Bs + (size_t)(p * 256 + (t & ~63)) * 8), 16, 0, 0);
    }
  };

  f32x4 acc[FM][FN];
  f32x4 zero = {0.f, 0.f, 0.f, 0.f};
  #pragma unroll
  for (int m = 0; m < FM; ++m)
    #pragma unroll
    for (int n = 0; n < FN; ++n) acc[m][n] = zero;

  for (int kt = 0; kt < nk; ++kt) {
    stage(kt);
    __syncthreads();
    #pragma unroll
    for (int ks = 0; ks < 2; ++ks) {
      s16x8 af[FM], bfv[FN];
      #pragma unroll
      for (int m = 0; m < FM; ++m) {
        int row = wr * (FM * 16) + m * 16 + lr;
        af[m] = *(const s16x8*)(As + row * 64 + (((ks * 4 + gq) ^ (row & 7)) << 3));
      }
      #pragma unroll
      for (int n = 0; n < FN; ++n) {
        int row = wc * (FN * 16) + n * 16 + lr;
        bfv[n] = *(const s16x8*)(Bs + row * 64 + (((ks * 4 + gq) ^ (row & 7)) << 3));
      }
      __builtin_amdgcn_s_setprio(1);
      #pragma unroll
      for (int m = 0; m < FM; ++m)
        #pragma unroll
        for (int n = 0; n < FN; ++n)
          acc[m][n] = __builtin_amdgcn_mfma_f32_16x16x32_bf16(af[m], bfv[n], acc[m][n], 0, 0, 0);
      __builtin_amdgcn_s_setprio(0);
    }
    __syncthreads();
  }

  float qs = 1.0f;
  if (g.kind == 3 && g.sp) qs = 0.125f / parse_scalar(g.sp) * 1.4426950408889634f;
  #pragma unroll
  for (int n = 0; n < FN; ++n) {
    int col = n0 + wc * (FN * 16) + n * 16 + lr;
    int seg = col >> 9, cm = col & 511;
    float bv;
    if (g.kind == 3) bv = (seg == 0) ? g.b0[cm] : (seg == 1) ? g.b1[cm] : g.b2[cm];
    else bv = g.b0 ? g.b0[col] : 0.f;
    #pragma unroll
    for (int m = 0; m < FM; ++m) {
      int rowb = m0 + wr * (FM * 16) + m * 16 + 4 * gq;
      if (g.kind == 3) {
        if (seg == 2) {
          int d = cm & 63, hh = cm >> 6, bb = rowb >> 10, s = rowb & 1023;
          ushort4 pk;
          pk.x = f2bf(acc[m][n][0] + bv); pk.y = f2bf(acc[m][n][1] + bv);
          pk.z = f2bf(acc[m][n][2] + bv); pk.w = f2bf(acc[m][n][3] + bv);
          *(ushort4*)(g.vto + (((size_t)(bb * 8 + hh) * 64 + d) << 10) + s) = pk;
        } else if (seg == 1) {
          #pragma unroll
          for (int r = 0; r < 4; ++r)
            g.ko[(size_t)(rowb + r) * 512 + cm] = f2bf(acc[m][n][r] + bv);
        } else {
          #pragma unroll
          for (int r = 0; r < 4; ++r)
            g.qo[(size_t)(rowb + r) * 512 + cm] = f2bf((acc[m][n][r] + bv) * qs);
        }
      } else {
        #pragma unroll
        for (int r = 0; r < 4; ++r) {
          float v = acc[m][n][r] + bv;
          if (g.kind == 2) v = gelu_fast(v);
          if (g.kind == 0) g.outf[(size_t)(rowb + r) * g.N + col] = v;
          else g.outb[(size_t)(rowb + r) * g.N + col] = f2bf(v);
        }
      }
    }
  }
}

// ---------------- flash attention core v3 (unchanged, passing)
__global__ __launch_bounds__(256)
void attn_core(const ushort* __restrict__ Q0, const ushort* __restrict__ K0,
               const ushort* __restrict__ V0, ushort* __restrict__ O0,
               const ushort* __restrict__ Q1, const ushort* __restrict__ K1,
               const ushort* __restrict__ V1, ushort* __restrict__ O1)
{
  __shared__ ushort Ks[2][64 * 64];
  __shared__ ushort Vs[2][64 * 64];
  __shared__ ushort Ps[4][1024];
  const int str = blockIdx.y;
  const ushort* Q = str ? Q1 : Q0;
  const ushort* Kx = str ? K1 : K0;
  const ushort* VT = str ? V1 : V0;
  ushort* O = str ? O1 : O0;

  const int t = threadIdx.x, lane = t & 63, w = t >> 6;
  const int lr = lane & 15, g = lane >> 4;
  int bid = blockIdx.x;
  int L = (bid & 7) * 64 + (bid >> 3);
  int bh = L >> 4, qt = L & 15;
  size_t tbase = ((size_t)(bh >> 3) << 19) + ((size_t)(bh & 7) << 6);
  const ushort* Kbase = Kx + tbase;
  const ushort* Vbase = VT + ((size_t)bh << 16);
  int q0 = qt * 64 + w * 16;
  char* myPs = (char*)Ps[w];
  const int psw = (lr & 7) << 4;

  auto stage = [&](int kt, int buf) {
    #pragma unroll
    for (int p = 0; p < 2; ++p) {
      int c = p * 256 + t, row = c >> 3, sl = c & 7;
      const ushort* src = Kbase + (size_t)(kt * 64 + row) * 512 + ((sl ^ (row & 7)) << 3);
      __builtin_amdgcn_global_load_lds((const AS1 void*)src,
          (AS3 void*)(Ks[buf] + (size_t)(p * 256 + (t & ~63)) * 8), 16, 0, 0);
    }
    #pragma unroll
    for (int p = 0; p < 2; ++p) {
      int c = p * 256 + t, row = c >> 3, sl = c & 7;
      const ushort* src = Vbase + (size_t)row * 1024 + kt * 64 + ((sl ^ (row & 7)) << 3);
      __builtin_amdgcn_global_load_lds((const AS1 void*)src,
          (AS3 void*)(Vs[buf] + (size_t)(p * 256 + (t & ~63)) * 8), 16, 0, 0);
    }
  };

  s16x8 qf[2];
  #pragma unroll
  for (int ks = 0; ks < 2; ++ks)
    qf[ks] = *(const s16x8*)(Q + tbase + (size_t)(q0 + lr) * 512 + ks * 32 + g * 8);

  f32x4 po[4];
  f32x4 zero = {0.f, 0.f, 0.f, 0.f};
  #pragma unroll
  for (int dt = 0; dt < 4; ++dt) po[dt] = zero;
  float mrow = -1e30f, lsum = 0.f;

  stage(0, 0);
  __syncthreads();
  #pragma unroll 2
  for (int kt = 0; kt < 16; ++kt) {
    int cur = kt & 1;
    const ushort* Kb = Ks[cur];
    const ushort* Vb = Vs[cur];
    if (kt < 15) stage(kt + 1, cur ^ 1);

    f32x4 sc[4];
    #pragma unroll
    for (int c = 0; c < 4; ++c) {
      sc[c] = zero;
      #pragma unroll
      for (int ks = 0; ks < 2; ++ks) {
        int row = c * 16 + lr;
        s16x8 kf = *(const s16x8*)(Kb + row * 64 + (((ks * 4 + g) ^ (row & 7)) << 3));
        sc[c] = __builtin_amdgcn_mfma_f32_16x16x32_bf16(kf, qf[ks], sc[c], 0, 0, 0);
      }
    }

    float tm = sc[0][0];
    #pragma unroll
    for (int c = 0; c < 4; ++c)
      #pragma unroll
      for (int r = 0; r < 4; ++r) tm = fmaxf(tm, sc[c][r]);
    tm = fmaxf(tm, __shfl_xor(tm, 16));
    tm = fmaxf(tm, __shfl_xor(tm, 32));
    float nm = fmaxf(mrow, tm);
    float fr = ex2(mrow - nm);
    float ts = 0.f;
    #pragma unroll
    for (int c = 0; c < 4; ++c)
      #pragma unroll
      for (int r = 0; r < 4; ++r) {
        float pv = ex2(sc[c][r] - nm);
        sc[c][r] = pv;
        ts += pv;
      }
    ts += __shfl_xor(ts, 16);
    ts += __shfl_xor(ts, 32);
    lsum = lsum * fr + ts;
    mrow = nm;
    #pragma unroll
    for (int dt = 0; dt < 4; ++dt) po[dt] *= fr;

    #pragma unroll
    for (int c = 0; c < 4; ++c) {
      uint2 d;
      d.x = cvt_pk_bf16(sc[c][0], sc[c][1]);
      d.y = cvt_pk_bf16(sc[c][2], sc[c][3]);
      *(uint2*)(myPs + lr * 128 + ((c * 32 + g * 8) ^ psw)) = d;
    }
    s16x8 paf[2];
    #pragma unroll
    for (int ks = 0; ks < 2; ++ks)
      paf[ks] = *(const s16x8*)(myPs + lr * 128 + ((ks * 64 + g * 16) ^ psw));

    __builtin_amdgcn_s_setprio(1);
    #pragma unroll
    for (int dt = 0; dt < 4; ++dt) {
      int vrow = dt * 16 + lr;
      #pragma unroll
      for (int ks = 0; ks < 2; ++ks) {
        s16x8 vf = *(const s16x8*)(Vb + vrow * 64 + (((ks * 4 + g) ^ (vrow & 7)) << 3));
        po[dt] = __builtin_amdgcn_mfma_f32_16x16x32_bf16(vf, paf[ks], po[dt], 0, 0, 0);
      }
    }
    __builtin_amdgcn_s_setprio(0);
    __syncthreads();
  }

  float inv = 1.0f / lsum;
  #pragma unroll
  for (int dt = 0; dt < 4; ++dt) {
    ushort4 pk;
    pk.x = f2bf(po[dt][0] * inv);
    pk.y = f2bf(po[dt][1] * inv);
    pk.z = f2bf(po[dt][2] * inv);
    pk.w = f2bf(po[dt][3] * inv);
    *(ushort4*)(O + tbase + (size_t)(q0 + lr) * 512 + dt * 16 + 4 * g) = pk;
  }
}

// ---------------- LN(a_f32 + b_bf16) -> bf16, batched pair
__global__ __launch_bounds__(256)
void add_ln_fb2(const float* __restrict__ a0, const ushort* __restrict__ b0,
                ushort* __restrict__ o0, const float* __restrict__ a1,
                const ushort* __restrict__ b1, ushort* __restrict__ o1,
                const float* __restrict__ nsc, const float* __restrict__ nbi,
                int i0, int i1)
{
  const float* a = blockIdx.y ? a1 : a0;
  const ushort* b = blockIdx.y ? b1 : b0;
  ushort* outb = blockIdx.y ? o1 : o0;
  const float* scale = nsc + (blockIdx.y ? i1 : i0) * 512;
  const float* bias = nbi + (blockIdx.y ? i1 : i0) * 512;
  const int lane = threadIdx.x & 63, w = threadIdx.x >> 6;
  const size_t row = blockIdx.x * 4 + w;
  s16x8 bv8 = *(const s16x8*)(b + row * 512 + lane * 8);
  float x[8];
  #pragma unroll
  for (int j = 0; j < 8; j += 4) {
    float4 av = *(const float4*)(a + row * 512 + lane * 8 + j);
    x[j] = av.x + bf2f((ushort)bv8[j]);
    x[j + 1] = av.y + bf2f((ushort)bv8[j + 1]);
    x[j + 2] = av.z + bf2f((ushort)bv8[j + 2]);
    x[j + 3] = av.w + bf2f((ushort)bv8[j + 3]);
  }
  float s = 0.f, ss = 0.f;
  #pragma unroll
  for (int j = 0; j < 8; ++j) { s += x[j]; ss += x[j] * x[j]; }
  #pragma unroll
  for (int m = 1; m < 64; m <<= 1) { s += __shfl_xor(s, m); ss += __shfl_xor(ss, m); }
  float mu = s * (1.f / 512.f);
  float rstd = rsqrtf(ss * (1.f / 512.f) - mu * mu + 1e-5f);
  ushort o[8];
  #pragma unroll
  for (int j = 0; j < 8; ++j) {
    int e = lane * 8 + j;
    o[j] = f2bf((x[j] - mu) * rstd * scale[e] + bias[e]);
  }
  *(s16x8*)(outb + row * 512 + lane * 8) = *(s16x8*)o;
}

// ---------------- LN(a_bf16 + b_bf16) -> f32 final, batched pair
__global__ __launch_bounds__(256)
void add_ln_bb2(const ushort* __restrict__ a0, const ushort* __restrict__ b0,
                float* __restrict__ o0, const ushort* __restrict__ a1,
                const ushort* __restrict__ b1, float* __restrict__ o1,
                const float* __restrict__ nsc, const float* __restrict__ nbi,
                int i0, int i1)
{
  const ushort* a = blockIdx.y ? a1 : a0;
  const ushort* b = blockIdx.y ? b1 : b0;
  float* outf = blockIdx.y ? o1 : o0;
  const float* scale = nsc + (blockIdx.y ? i1 : i0) * 512;
  const float* bias = nbi + (blockIdx.y ? i1 : i0) * 512;
  const int lane = threadIdx.x & 63, w = threadIdx.x >> 6;
  const size_t row = blockIdx.x * 4 + w;
  s16x8 av = *(const s16x8*)(a + row * 512 + lane * 8);
  s16x8 bv = *(const s16x8*)(b + row * 512 + lane * 8);
  float x[8];
  #pragma unroll
  for (int j = 0; j < 8; ++j)
    x[j] = bf2f((ushort)av[j]) + bf2f((ushort)bv[j]);
  float s = 0.f, ss = 0.f;
  #pragma unroll
  for (int j = 0; j < 8; ++j) { s += x[j]; ss += x[j] * x[j]; }
  #pragma unroll
  for (int m = 1; m < 64; m <<= 1) { s += __shfl_xor(s, m); ss += __shfl_xor(ss, m); }
  float mu = s * (1.f / 512.f);
  float rstd = rsqrtf(ss * (1.f / 512.f) - mu * mu + 1e-5f);
  float o[8];
  #pragma unroll
  for (int j = 0; j < 8; ++j) {
    int e = lane * 8 + j;
    o[j] = (x[j] - mu) * rstd * scale[e] + bias[e];
  }
  *(float4*)(outf + row * 512 + lane * 8) = *(float4*)o;
  *(float4*)(outf + row * 512 + lane * 8 + 4) = *(float4*)(o + 4);
}

// ---------------- gated merge + LN, bf16 in/out, batched pair
__global__ __launch_bounds__(256)
void gate_ln2(const ushort* __restrict__ x0, const ushort* __restrict__ c0,
              ushort* __restrict__ o0, const ushort* __restrict__ x1,
              const ushort* __restrict__ c1, ushort* __restrict__ o1,
              const float* __restrict__ gw, const float* __restrict__ gb,
              const float* __restrict__ scale, const float* __restrict__ bias)
{
  const ushort* x = blockIdx.y ? x1 : x0;
  const ushort* cr = blockIdx.y ? c1 : c0;
  ushort* outb = blockIdx.y ? o1 : o0;
  const int lane = threadIdx.x & 63, w = threadIdx.x >> 6;
  const size_t row = blockIdx.x * 4 + w;
  s16x8 xv8 = *(const s16x8*)(x + row * 512 + lane * 8);
  s16x8 cv8 = *(const s16x8*)(cr + row * 512 + lane * 8);
  float xv[8], cv[8];
  #pragma unroll
  for (int j = 0; j < 8; ++j) { xv[j] = bf2f((ushort)xv8[j]); cv[j] = bf2f((ushort)cv8[j]); }
  float d0 = 0.f, d1 = 0.f;
  #pragma unroll
  for (int j = 0; j < 8; ++j) {
    int e = lane * 8 + j;
    float2 g0 = *(const float2*)(gw + 2 * e);
    float2 g1 = *(const float2*)(gw + 2 * (512 + e));
    d0 += xv[j] * g0.x + cv[j] * g1.x;
    d1 += xv[j] * g0.y + cv[j] * g1.y;
  }
  #pragma unroll
  for (int m = 1; m < 64; m <<= 1) { d0 += __shfl_xor(d0, m); d1 += __shfl_xor(d1, m); }
  d0 += gb[0]; d1 += gb[1];
  float mx = fmaxf(d0, d1);
  float e0 = __expf(d0 - mx), e1 = __expf(d1 - mx);
  float inv = 1.0f / (e0 + e1);
  float g0w = e0 * inv, g1w = e1 * inv;
  float xc[8];
  float s = 0.f, ss = 0.f;
  #pragma unroll
  for (int j = 0; j < 8; ++j) {
    xc[j] = xv[j] * g0w + cv[j] * g1w;
    s += xc[j]; ss += xc[j] * xc[j];
  }
  #pragma unroll
  for (int m = 1; m < 64; m <<= 1) { s += __shfl_xor(s, m); ss += __shfl_xor(ss, m); }
  float mu = s * (1.f / 512.f);
  float rstd = rsqrtf(ss * (1.f / 512.f) - mu * mu + 1e-5f);
  ushort o[8];
  #pragma unroll
  for (int j = 0; j < 8; ++j) {
    int e = lane * 8 + j;
    o[j] = f2bf((xc[j] - mu) * rstd * scale[e] + bias[e]);
  }
  *(s16x8*)(outb + row * 512 + lane * 8) = *(s16x8*)o;
}

extern "C" void kernel_launch(void* const* d_in, const int* in_sizes, int n_in,
                              void* d_out, int out_size, void* d_ws, size_t ws_size,
                              hipStream_t stream)
{
  (void)in_sizes; (void)n_in; (void)out_size; (void)ws_size;
  const int T = 4096, E = 512, HD = 2048;
  const float* body = (const float*)d_in[0];
  const float* limb = (const float*)d_in[1];
  const float* qw = (const float*)d_in[2];  const float* qb = (const float*)d_in[3];
  const float* kw = (const float*)d_in[4];  const float* kb = (const float*)d_in[5];
  const float* vw = (const float*)d_in[6];  const float* vb = (const float*)d_in[7];
  const float* ow = (const float*)d_in[8];  const float* ob = (const float*)d_in[9];
  const float* w1 = (const float*)d_in[10]; const float* fb1 = (const float*)d_in[11];
  const float* w2 = (const float*)d_in[12]; const float* fb2 = (const float*)d_in[13];
  const float* nsc = (const float*)d_in[14]; const float* nbi = (const float*)d_in[15];
  const float* gw = (const float*)d_in[16];  const float* gb = (const float*)d_in[17];
  const void* temp = d_in[18];

  char* ws = (char*)d_ws;
  size_t off = 0;
  auto alloc = [&](size_t b) { char* p = ws + off; off += (b + 255) & ~(size_t)255; return p; };
  ushort* FW    = (ushort*)alloc((size_t)4 * 1536 * 512 * 2);
  ushort* WOT   = (ushort*)alloc((size_t)4 * E * E * 2);
  ushort* W1T   = (ushort*)alloc((size_t)2 * E * HD * 2);
  ushort* W2T   = (ushort*)alloc((size_t)2 * HD * E * 2);
  ushort* XB    = (ushort*)alloc((size_t)T * E * 2);
  ushort* XL    = (ushort*)alloc((size_t)T * E * 2);
  ushort* PROJA = (ushort*)alloc((size_t)T * E * 2);
  ushort* PROJB = (ushort*)alloc((size_t)T * E * 2);
  ushort* BODYb = (ushort*)alloc((size_t)T * E * 2);
  ushort* LIMBb = (ushort*)alloc((size_t)T * E * 2);
  ushort* BCRb  = (ushort*)alloc((size_t)T * E * 2);
  ushort* LCRb  = (ushort*)alloc((size_t)T * E * 2);
  ushort* GBb   = (ushort*)alloc((size_t)T * E * 2);
  ushort* GLb   = (ushort*)alloc((size_t)T * E * 2);
  ushort* QA    = (ushort*)alloc((size_t)T * E * 2);
  ushort* KA    = (ushort*)alloc((size_t)T * E * 2);
  ushort* VTA   = (ushort*)alloc((size_t)T * E * 2);
  ushort* QB    = (ushort*)alloc((size_t)T * E * 2);
  ushort* KB    = (ushort*)alloc((size_t)T * E * 2);
  ushort* VTB   = (ushort*)alloc((size_t)T * E * 2);
  ushort* AOA   = (ushort*)alloc((size_t)T * E * 2);
  ushort* AOB   = (ushort*)alloc((size_t)T * E * 2);
  ushort* H1A   = QA;     // 16 MB spans QA,KA,VTA,QB (dead by FFN)
  ushort* H1B   = KB;     // 16 MB spans KB,VTB,AOA,AOB (dead by FFN)
  ushort* F2A   = PROJA;  // FFN2 bf16 out, reuse
  ushort* F2B   = PROJB;

  transpose_all<<<12288, dim3(32, 8), 0, stream>>>(qw, kw, vw, ow, w1, w2, body, limb,
                                                   FW, WOT, W1T, W2T, XB, XL);

  auto qkv_pair = [&](const ushort* A0, int t0, ushort* q0, ushort* k0, ushort* v0,
                      const ushort* A1, int t1, ushort* q1, ushort* k1, ushort* v1) {
    GemmArgs a{}, b{};
    int kv0 = t0 ^ (t0 >> 1), kv1 = t1 ^ (t1 >> 1);
    a.A = A0; a.Bt = FW + (size_t)t0 * 1536 * 512;
    a.b0 = qb + t0 * E; a.b1 = kb + kv0 * E; a.b2 = vb + kv0 * E;
    a.qo = q0; a.ko = k0; a.vto = v0; a.sp = temp; a.M = T; a.N = 1536; a.K = E; a.kind = 3;
    b = a;
    b.A = A1; b.Bt = FW + (size_t)t1 * 1536 * 512;
    b.b0 = qb + t1 * E; b.b1 = kb + kv1 * E; b.b2 = vb + kv1 * E;
    b.qo = q1; b.ko = k1; b.vto = v1;
    gemm_k<4, 4><<<dim3(12, 32, 2), 256, 0, stream>>>(a, b);
  };
  auto oproj_pair = [&](const ushort* A0, int i0, ushort* ob0,
                        const ushort* A1, int i1, ushort* ob1) {
    GemmArgs a{}, b{};
    a.A = A0; a.Bt = WOT + (size_t)i0 * E * E; a.b0 = ob + i0 * E;
    a.outb = ob0; a.M = T; a.N = E; a.K = E; a.kind = 1;
    b = a;
    b.A = A1; b.Bt = WOT + (size_t)i1 * E * E; b.b0 = ob + i1 * E;
    b.outb = ob1;
    gemm_k<2, 4><<<dim3(4, 64, 2), 256, 0, stream>>>(a, b);
  };

  // ---- self attention (both streams batched)
  qkv_pair(XB, 0, QA, KA, VTA, XL, 1, QB, KB, VTB);
  attn_core<<<dim3(512, 2), 256, 0, stream>>>(QA, KA, VTA, AOA, QB, KB, VTB, AOB);
  oproj_pair(AOA, 0, PROJA, AOB, 1, PROJB);
  add_ln_fb2<<<dim3(T / 4, 2), 256, 0, stream>>>(body, PROJA, BODYb, limb, PROJB, LIMBb,
                                                 nsc, nbi, 0, 3);
  // ---- cross attention
  qkv_pair(BODYb, 2, QA, KA, VTA, LIMBb, 3, QB, KB, VTB);
  attn_core<<<dim3(512, 2), 256, 0, stream>>>(QA, KB, VTB, AOA, QB, KA, VTA, AOB);
  oproj_pair(AOA, 2, BCRb, AOB, 3, LCRb);

  // ---- gated merge + LN (norm index 1 for BOTH, faithful to reference)
  gate_ln2<<<dim3(T / 4, 2), 256, 0, stream>>>(BODYb, BCRb, GBb, LIMBb, LCRb, GLb,
                                               gw, gb, nsc + E, nbi + E);

  // ---- FFN + residual LN -> final outputs
  {
    GemmArgs a{}, b{};
    a.A = GBb; a.Bt = W1T; a.b0 = fb1; a.outb = H1A;
    a.M = T; a.N = HD; a.K = E; a.kind = 2;
    b = a; b.A = GLb; b.Bt = W1T + (size_t)HD * E; b.b0 = fb1 + HD; b.outb = H1B;
    gemm_k<4, 4><<<dim3(16, 32, 2), 256, 0, stream>>>(a, b);
  }
  {
    GemmArgs a{}, b{};
    a.A = H1A; a.Bt = W2T; a.b0 = fb2; a.outb = F2A;
    a.M = T; a.N = E; a.K = HD; a.kind = 1;
    b = a; b.A = H1B; b.Bt = W2T + (size_t)HD * E; b.b0 = fb2 + E; b.outb = F2B;
    gemm_k<2, 4><<<dim3(4, 64, 2), 256, 0, stream>>>(a, b);
  }
  add_ln_bb2<<<dim3(T / 4, 2), 256, 0, stream>>>(GBb, F2A, (float*)d_out,
                                                 GLb, F2B, (float*)d_out + (size_t)T * E,
                                                 nsc, nbi, 2, 5);
}